// Round 9
// baseline (2244.059 us; speedup 1.0000x reference)
//
#include <hip/hip_runtime.h>
#include <hip/hip_bf16.h>
#include <hip/hip_fp16.h>
#include <math.h>

#define NP 20000
#define NL 4000
#define NQ 12000
#define NE 160000
#define DD 128
#define N3 384
#define TT 8
#define FR 512   // 64 lanes * 8 elems per fragment slot

typedef __attribute__((ext_vector_type(8))) short bf16x8;
typedef __attribute__((ext_vector_type(4))) float f32x4;

// ---------- device global scratch ----------
__device__ float g_path [NP * DD];
__device__ float g_link [NL * DD];
__device__ float g_queue[NQ * DD];
// gate-contiguous fp16 projections: [row][col(128)][4] (slots 0..2 = z,r,h gates)
__device__ __align__(16) unsigned short g_qgi_h[NQ * 512];
__device__ __align__(16) unsigned short g_lgi_h[NL * 512];
__device__ int   g_peq  [NE];
__device__ int   g_pel  [NE];
__device__ int   g_counts[NQ];
__device__ int   g_off  [NQ + 1];
__device__ int   g_cur  [NQ];
__device__ int   g_col  [NE];
__device__ int   g_nzq  [NQ];
__device__ int   g_nzl  [NL];
// weight packs, MFMA B-fragment layout: [nt][kc_total][lane=64][j=8], hi/lo split bf16
__device__ unsigned short g_upb_hi[24*4*FR], g_upb_lo[24*4*FR];        // Up
__device__ unsigned short g_wpb_hi[2*24*4*FR], g_wpb_lo[2*24*4*FR];    // Wp (2 halves)
__device__ unsigned short g_wlb_hi[24*4*FR], g_wlb_lo[24*4*FR];        // Wl
__device__ unsigned short g_wuq_hi[24*8*FR], g_wuq_lo[24*8*FR];        // [Wq;Uq] K=256
__device__ unsigned short g_ulb_hi[24*4*FR], g_ulb_lo[24*4*FR];        // Ul
__device__ unsigned short g_w1b_hi[16*4*FR], g_w1b_lo[16*4*FR];        // Wr1
__device__ unsigned short g_w2b_hi[16*8*FR], g_w2b_lo[16*8*FR];        // Wr2

__device__ __forceinline__ float fsig(float x)  { return 1.0f / (1.0f + __expf(-x)); }
__device__ __forceinline__ float ftanh(float x) { return 2.0f / (1.0f + __expf(-2.0f * x)) - 1.0f; }

__device__ __forceinline__ void split_bf(float v, unsigned short& hi, unsigned short& lo) {
    unsigned u = __float_as_uint(v);
    hi = (unsigned short)(u >> 16);
    float lof = v - __uint_as_float(u & 0xFFFF0000u);
    lo = (unsigned short)(__float_as_uint(lof) >> 16);
}
__device__ __forceinline__ unsigned short f2h(float v) {
    __half h = __float2half_rn(v);
    return *reinterpret_cast<unsigned short*>(&h);
}
__device__ __forceinline__ float h2f(unsigned short u) {
    __half h = *reinterpret_cast<__half*>(&u);
    return __half2float(h);
}
__device__ __forceinline__ void h2x2(unsigned u, float& a, float& b) {
    __half2 h = *reinterpret_cast<__half2*>(&u);
    float2 f = __half22float2(h);
    a = f.x; b = f.y;
}

// ---------- setup kernels ----------
__global__ void k_init_maps() {
    int i = blockIdx.x * 256 + threadIdx.x;
    if (i < NE) { g_peq[i] = -1; g_pel[i] = -1; }
    if (i < NQ) { g_counts[i] = 0; }
}

__global__ void k_fill_maps(const int* __restrict__ path_ids, const int* __restrict__ l_q_p,
                            const int* __restrict__ l_p_s, const int* __restrict__ queue_to_path,
                            const int* __restrict__ link_to_path, const int* __restrict__ sequence_queues) {
    int i = blockIdx.x * 256 + threadIdx.x;
    if (i < NE) {
        int p = path_ids[i];
        g_peq[p * 8 + l_q_p[i]] = queue_to_path[i];
        g_pel[p * 8 + l_p_s[i]] = link_to_path[i];
        atomicAdd(&g_counts[sequence_queues[i]], 1);
    }
}

__global__ __launch_bounds__(1024) void k_scan() {
    __shared__ int part[1024];
    int tid = threadIdx.x;
    int base = tid * 12;
    int local[12];
    int s = 0;
#pragma unroll
    for (int j = 0; j < 12; j++) {
        int idx = base + j;
        int v = (idx < NQ) ? g_counts[idx] : 0;
        local[j] = s; s += v;
    }
    part[tid] = s;
    __syncthreads();
    for (int off = 1; off < 1024; off <<= 1) {
        int v = (tid >= off) ? part[tid - off] : 0;
        __syncthreads();
        part[tid] += v;
        __syncthreads();
    }
    int pre = (tid > 0) ? part[tid - 1] : 0;
#pragma unroll
    for (int j = 0; j < 12; j++) {
        int idx = base + j;
        if (idx < NQ) { g_off[idx] = pre + local[j]; g_cur[idx] = pre + local[j]; }
    }
    if (tid == 1023) g_off[NQ] = part[1023];
}

__global__ void k_fill_csr(const int* __restrict__ sequence_queues, const int* __restrict__ path_to_queue) {
    int i = blockIdx.x * 256 + threadIdx.x;
    if (i < NE) {
        int q = sequence_queues[i];
        int pos = atomicAdd(&g_cur[q], 1);
        g_col[pos] = path_to_queue[i];
    }
}

__global__ void k_init_states(const float* __restrict__ traffic, const float* __restrict__ packets,
                              const float* __restrict__ capacity, const int* __restrict__ policy,
                              const float* __restrict__ weight, const int* __restrict__ priority) {
    int idx = blockIdx.x * 256 + threadIdx.x;
    if (idx < NP * DD) {
        int p = idx >> 7, d = idx & 127;
        g_path[idx] = (d == 0) ? traffic[p] : (d == 1) ? packets[p] : 0.0f;
    }
    if (idx < NL * DD) {
        int l = idx >> 7, d = idx & 127;
        float v = 0.0f;
        if (d == 0) v = capacity[l];
        else if (d >= 1 && d <= 3) v = (policy[l] == d - 1) ? 1.0f : 0.0f;
        g_link[idx] = v;
    }
    if (idx < NQ * DD) {
        int q = idx >> 7, d = idx & 127;
        float v = 0.0f;
        if (d < 3) v = (priority[q] == d) ? 1.0f : 0.0f;
        else if (d == 3) v = weight[q];
        g_queue[idx] = v;
    }
}

// generic weight pack: W[k][col] -> fragment layout, split bf16 hi/lo
// modes: 0=Up 1=Wp.q 2=Wp.l 3=Wl 4=Wq(kcb0) 5=Uq(kcb4) 6=Ul 7=Wr1 8=Wr2
__global__ void k_pack(int mode, const float* __restrict__ W, int ldn) {
    unsigned short *dhi, *dlo;
    int nt_cnt, kc_cnt, kc_total, kc_base;
    if (mode == 0)      { dhi=g_upb_hi; dlo=g_upb_lo; nt_cnt=24; kc_cnt=4; kc_total=4; kc_base=0; }
    else if (mode == 1) { dhi=g_wpb_hi; dlo=g_wpb_lo; nt_cnt=24; kc_cnt=4; kc_total=4; kc_base=0; }
    else if (mode == 2) { dhi=g_wpb_hi+24*4*FR; dlo=g_wpb_lo+24*4*FR; nt_cnt=24; kc_cnt=4; kc_total=4; kc_base=0; }
    else if (mode == 3) { dhi=g_wlb_hi; dlo=g_wlb_lo; nt_cnt=24; kc_cnt=4; kc_total=4; kc_base=0; }
    else if (mode == 4) { dhi=g_wuq_hi; dlo=g_wuq_lo; nt_cnt=24; kc_cnt=4; kc_total=8; kc_base=0; }
    else if (mode == 5) { dhi=g_wuq_hi; dlo=g_wuq_lo; nt_cnt=24; kc_cnt=4; kc_total=8; kc_base=4; }
    else if (mode == 6) { dhi=g_ulb_hi; dlo=g_ulb_lo; nt_cnt=24; kc_cnt=4; kc_total=4; kc_base=0; }
    else if (mode == 7) { dhi=g_w1b_hi; dlo=g_w1b_lo; nt_cnt=16; kc_cnt=4; kc_total=4; kc_base=0; }
    else                { dhi=g_w2b_hi; dlo=g_w2b_lo; nt_cnt=16; kc_cnt=8; kc_total=8; kc_base=0; }
    int tot = nt_cnt * kc_cnt * FR;
    int idx = blockIdx.x * 256 + threadIdx.x;
    if (idx >= tot) return;
    int j = idx & 7, lane = (idx >> 3) & 63;
    int kc = (idx >> 9) % kc_cnt, nt = idx / (kc_cnt * FR);
    int k = kc * 32 + (lane >> 4) * 8 + j;
    int col = nt * 16 + (lane & 15);
    float v = W[(size_t)k * ldn + col];
    unsigned short hi, lo;
    split_bf(v, hi, lo);
    size_t o = ((size_t)(nt * kc_total + kc_base + kc)) * FR + (size_t)lane * 8 + j;
    dhi[o] = hi; dlo[o] = lo;
}

// initial nonzero flags
__global__ void k_nz(int mode) {
    const float* st = mode ? g_link : g_queue;
    int n = mode ? NL : NQ;
    int* outf = mode ? g_nzl : g_nzq;
    int w = threadIdx.x >> 6, lane = threadIdx.x & 63;
    int row = blockIdx.x * 4 + w;
    if (row < n) {
        const float* r = st + (size_t)row * DD;
        bool nz = (r[lane] != 0.0f) || (r[lane + 64] != 0.0f);
        unsigned long long b = __ballot(nz);
        if (lane == 0) outf[row] = (b != 0ULL) ? 1 : 0;
    }
}

// ---------- merged path-phase projection GEMM -> gate-contiguous fp16 ----------
// blocks [0, NQ/16): g_queue @ Wp.q + bp0 -> g_qgi_h ; [NQ/16, +NL/16): g_link @ Wp.l -> g_lgi_h
__global__ __launch_bounds__(256) void k_gemm_mfma(const float* __restrict__ bias) {
    const float* A; unsigned short* C; const unsigned short *Bh, *Bl;
    int r0; bool useB;
    if (blockIdx.x < NQ / 16) {
        A = g_queue; C = g_qgi_h; Bh = g_wpb_hi; Bl = g_wpb_lo;
        r0 = blockIdx.x * 16; useB = true;
    } else {
        A = g_link; C = g_lgi_h; Bh = g_wpb_hi + 24*4*FR; Bl = g_wpb_lo + 24*4*FR;
        r0 = (blockIdx.x - NQ / 16) * 16; useB = false;
    }
    __shared__ unsigned short as_hi[16][136], as_lo[16][136];
    const int tid = threadIdx.x, w = tid >> 6, l = tid & 63;
    for (int idx = tid; idx < 16 * DD; idx += 256) {
        unsigned short hi, lo;
        split_bf(A[(size_t)r0 * DD + idx], hi, lo);
        as_hi[idx >> 7][idx & 127] = hi; as_lo[idx >> 7][idx & 127] = lo;
    }
    __syncthreads();
    f32x4 acc[6];
#pragma unroll
    for (int n = 0; n < 6; n++) acc[n] = (f32x4){0.f, 0.f, 0.f, 0.f};
#pragma unroll
    for (int kc = 0; kc < 4; kc++) {
        int kk = kc * 32 + (l >> 4) * 8;
        bf16x8 ah = *reinterpret_cast<const bf16x8*>(&as_hi[l & 15][kk]);
        bf16x8 al = *reinterpret_cast<const bf16x8*>(&as_lo[l & 15][kk]);
#pragma unroll
        for (int n = 0; n < 6; n++) {
            int nt = 6 * w + n;
            size_t boff = ((size_t)(nt * 4 + kc)) * FR + (size_t)l * 8;
            bf16x8 bhv = *reinterpret_cast<const bf16x8*>(&Bh[boff]);
            bf16x8 blv = *reinterpret_cast<const bf16x8*>(&Bl[boff]);
            acc[n] = __builtin_amdgcn_mfma_f32_16x16x32_bf16(ah, bhv, acc[n], 0, 0, 0);
            acc[n] = __builtin_amdgcn_mfma_f32_16x16x32_bf16(al, bhv, acc[n], 0, 0, 0);
            acc[n] = __builtin_amdgcn_mfma_f32_16x16x32_bf16(ah, blv, acc[n], 0, 0, 0);
        }
    }
    const int rbase = (l >> 4) * 4;
#pragma unroll
    for (int n = 0; n < 6; n++) {
        int nt = 6 * w + n;
        int gate = nt >> 3, wc = (nt & 7) * 16 + (l & 15);
        float bv = useB ? bias[gate * 128 + wc] : 0.f;
#pragma unroll
        for (int i = 0; i < 4; i++)
            C[(size_t)(r0 + rbase + i) * 512 + wc * 4 + gate] = f2h(acc[n][i] + bv);
    }
}

// ---------- fused path GRU: MFMA + 8B gathers + one-step-ahead prefetch ----------
__global__ __launch_bounds__(256) void k_path(const float* __restrict__ bp) {
    __shared__ unsigned short hs_hi[2][16][136];
    __shared__ unsigned short hs_lo[2][16][136];
    __shared__ int qqA[8][16], llA[8][16], mAsh[8][16];
    const int tid = threadIdx.x;
    const int w = tid >> 6, l = tid & 63;
    const int r0 = blockIdx.x * 16;
    if (tid < 128) {
        int r = tid >> 3, t = tid & 7;
        int e = (r0 + r) * 8 + t;
        int qq = g_peq[e], ll = g_pel[e];
        qqA[t][r] = qq; llA[t][r] = ll;
        mAsh[t][r] = (g_nzq[qq] | g_nzl[ll]);
    }
    const int c0 = 32 * w + (l & 15), c1 = c0 + 16;
    const int rbase = (l >> 4) * 4;
    float h0[4], h1[4];
#pragma unroll
    for (int i = 0; i < 4; i++) {
        h0[i] = g_path[(size_t)(r0 + rbase + i) * DD + c0];
        h1[i] = g_path[(size_t)(r0 + rbase + i) * DD + c1];
    }
#pragma unroll
    for (int i = 0; i < 4; i++) {
        unsigned short hi, lo;
        split_bf(h0[i], hi, lo); hs_hi[0][rbase + i][c0] = hi; hs_lo[0][rbase + i][c0] = lo;
        split_bf(h1[i], hi, lo); hs_hi[0][rbase + i][c1] = hi; hs_lo[0][rbase + i][c1] = lo;
    }
    __syncthreads();
    float bz[2], br[2], bh[2];
    bz[0] = bp[N3 + c0]; bz[1] = bp[N3 + c1];
    br[0] = bp[N3 + 128 + c0]; br[1] = bp[N3 + 128 + c1];
    bh[0] = bp[N3 + 256 + c0]; bh[1] = bp[N3 + 256 + c1];

    uint2 curQ[2][4], curL[2][4], nxtQ[2][4], nxtL[2][4];
    // prologue: gather t=0
#pragma unroll
    for (int tau = 0; tau < 2; tau++) {
        int cc = tau ? c1 : c0;
#pragma unroll
        for (int i = 0; i < 4; i++) {
            int q = qqA[0][rbase + i], lk = llA[0][rbase + i];
            curQ[tau][i] = *reinterpret_cast<const uint2*>(&g_qgi_h[(size_t)q * 512 + cc * 4]);
            curL[tau][i] = *reinterpret_cast<const uint2*>(&g_lgi_h[(size_t)lk * 512 + cc * 4]);
        }
    }

    for (int t = 0; t < TT; t++) {
        const int cur = t & 1, nxt = cur ^ 1;
        // prefetch t+1 gathers (consumed after one barrier; latency hidden by MFMA)
        if (t + 1 < TT) {
#pragma unroll
            for (int tau = 0; tau < 2; tau++) {
                int cc = tau ? c1 : c0;
#pragma unroll
                for (int i = 0; i < 4; i++) {
                    int q = qqA[t + 1][rbase + i], lk = llA[t + 1][rbase + i];
                    nxtQ[tau][i] = *reinterpret_cast<const uint2*>(&g_qgi_h[(size_t)q * 512 + cc * 4]);
                    nxtL[tau][i] = *reinterpret_cast<const uint2*>(&g_lgi_h[(size_t)lk * 512 + cc * 4]);
                }
            }
        }
        int msk[4];
#pragma unroll
        for (int i = 0; i < 4; i++) msk[i] = mAsh[t][rbase + i];

        bf16x8 ah[4], al[4];
#pragma unroll
        for (int kc = 0; kc < 4; kc++) {
            ah[kc] = *reinterpret_cast<const bf16x8*>(&hs_hi[cur][l & 15][kc * 32 + (l >> 4) * 8]);
            al[kc] = *reinterpret_cast<const bf16x8*>(&hs_lo[cur][l & 15][kc * 32 + (l >> 4) * 8]);
        }
        f32x4 acc[3][2];
#pragma unroll
        for (int g = 0; g < 3; g++)
#pragma unroll
            for (int tau = 0; tau < 2; tau++) acc[g][tau] = (f32x4){0.f, 0.f, 0.f, 0.f};
#pragma unroll
        for (int kc = 0; kc < 4; kc++) {
#pragma unroll
            for (int g = 0; g < 3; g++) {
#pragma unroll
                for (int tau = 0; tau < 2; tau++) {
                    int nt = g * 8 + 2 * w + tau;
                    size_t boff = ((size_t)(nt * 4 + kc) * 64 + l) * 8;
                    bf16x8 bhv = *reinterpret_cast<const bf16x8*>(&g_upb_hi[boff]);
                    bf16x8 blv = *reinterpret_cast<const bf16x8*>(&g_upb_lo[boff]);
                    acc[g][tau] = __builtin_amdgcn_mfma_f32_16x16x32_bf16(ah[kc], bhv, acc[g][tau], 0, 0, 0);
                    acc[g][tau] = __builtin_amdgcn_mfma_f32_16x16x32_bf16(al[kc], bhv, acc[g][tau], 0, 0, 0);
                    acc[g][tau] = __builtin_amdgcn_mfma_f32_16x16x32_bf16(ah[kc], blv, acc[g][tau], 0, 0, 0);
                }
            }
        }
        // epilogue: gates, h update, write other LDS buffer
#pragma unroll
        for (int tau = 0; tau < 2; tau++) {
#pragma unroll
            for (int i = 0; i < 4; i++) {
                float q0, q1, l0, l1;
                h2x2(curQ[tau][i].x, q0, q1);
                float q2 = h2f((unsigned short)(curQ[tau][i].y & 0xFFFFu));
                h2x2(curL[tau][i].x, l0, l1);
                float l2 = h2f((unsigned short)(curL[tau][i].y & 0xFFFFu));
                float zin = acc[0][tau][i] + q0 + l0 + bz[tau];
                float rin = acc[1][tau][i] + q1 + l1 + br[tau];
                float hold = tau ? h1[i] : h0[i];
                float zv = fsig(zin);
                float rv = fsig(rin);
                float cand = ftanh(q2 + l2 + rv * (acc[2][tau][i] + bh[tau]));
                float hn = zv * hold + (1.0f - zv) * cand;
                float hout = msk[i] ? hn : hold;
                if (tau) h1[i] = hout; else h0[i] = hout;
            }
        }
#pragma unroll
        for (int i = 0; i < 4; i++) {
            unsigned short hi, lo;
            split_bf(h0[i], hi, lo); hs_hi[nxt][rbase + i][c0] = hi; hs_lo[nxt][rbase + i][c0] = lo;
            split_bf(h1[i], hi, lo); hs_hi[nxt][rbase + i][c1] = hi; hs_lo[nxt][rbase + i][c1] = lo;
        }
        if (t + 1 < TT) {
#pragma unroll
            for (int tau = 0; tau < 2; tau++)
#pragma unroll
                for (int i = 0; i < 4; i++) { curQ[tau][i] = nxtQ[tau][i]; curL[tau][i] = nxtL[tau][i]; }
        }
        __syncthreads();
    }
#pragma unroll
    for (int i = 0; i < 4; i++) {
        g_path[(size_t)(r0 + rbase + i) * DD + c0] = h0[i];
        g_path[(size_t)(r0 + rbase + i) * DD + c1] = h1[i];
    }
}

// ---------- queue GRU via MFMA with in-kernel CSR segment sum ----------
__global__ __launch_bounds__(256) void k_queue_mfma(const float* __restrict__ bq) {
    __shared__ unsigned short xs_hi[16][136], xs_lo[16][136];
    __shared__ unsigned short hs_hi[16][136], hs_lo[16][136];
    __shared__ int nzf[16];
    const int tid = threadIdx.x, w = tid >> 6, l = tid & 63;
    const int r0 = blockIdx.x * 16;
    if (tid < 16) nzf[tid] = 0;
    // CSR segment sums: wave w handles queues 4w..4w+3; lane covers cols l, l+64
#pragma unroll
    for (int k = 0; k < 4; k++) {
        int ql = 4 * w + k;
        int q = r0 + ql;
        int s = g_off[q], e = g_off[q + 1];
        float a0 = 0.f, a1 = 0.f;
        for (int i = s; i < e; i++) {
            const float* p = g_path + (size_t)g_col[i] * DD;
            a0 += p[l]; a1 += p[l + 64];
        }
        unsigned short hi, lo;
        split_bf(a0, hi, lo); xs_hi[ql][l] = hi; xs_lo[ql][l] = lo;
        split_bf(a1, hi, lo); xs_hi[ql][l + 64] = hi; xs_lo[ql][l + 64] = lo;
    }
    for (int idx = tid; idx < 16 * DD; idx += 256) {
        unsigned short hi, lo;
        split_bf(g_queue[(size_t)r0 * DD + idx], hi, lo);
        hs_hi[idx >> 7][idx & 127] = hi; hs_lo[idx >> 7][idx & 127] = lo;
    }
    __syncthreads();
    f32x4 aZ[2], aR[2], aIH[2], aHH[2];
#pragma unroll
    for (int tau = 0; tau < 2; tau++) {
        aZ[tau] = (f32x4){0.f,0.f,0.f,0.f}; aR[tau] = (f32x4){0.f,0.f,0.f,0.f};
        aIH[tau] = (f32x4){0.f,0.f,0.f,0.f}; aHH[tau] = (f32x4){0.f,0.f,0.f,0.f};
    }
#pragma unroll
    for (int kc = 0; kc < 8; kc++) {
        int kk = (kc & 3) * 32 + (l >> 4) * 8;
        bf16x8 ah, al;
        if (kc < 4) {
            ah = *reinterpret_cast<const bf16x8*>(&xs_hi[l & 15][kk]);
            al = *reinterpret_cast<const bf16x8*>(&xs_lo[l & 15][kk]);
        } else {
            ah = *reinterpret_cast<const bf16x8*>(&hs_hi[l & 15][kk]);
            al = *reinterpret_cast<const bf16x8*>(&hs_lo[l & 15][kk]);
        }
#pragma unroll
        for (int g = 0; g < 3; g++) {
#pragma unroll
            for (int tau = 0; tau < 2; tau++) {
                int nt = g * 8 + 2 * w + tau;
                size_t boff = ((size_t)(nt * 8 + kc)) * FR + (size_t)l * 8;
                bf16x8 bhv = *reinterpret_cast<const bf16x8*>(&g_wuq_hi[boff]);
                bf16x8 blv = *reinterpret_cast<const bf16x8*>(&g_wuq_lo[boff]);
                f32x4 a = (g == 0) ? aZ[tau] : (g == 1) ? aR[tau] : (kc < 4 ? aIH[tau] : aHH[tau]);
                a = __builtin_amdgcn_mfma_f32_16x16x32_bf16(ah, bhv, a, 0, 0, 0);
                a = __builtin_amdgcn_mfma_f32_16x16x32_bf16(al, bhv, a, 0, 0, 0);
                a = __builtin_amdgcn_mfma_f32_16x16x32_bf16(ah, blv, a, 0, 0, 0);
                if (g == 0) aZ[tau] = a; else if (g == 1) aR[tau] = a;
                else { if (kc < 4) aIH[tau] = a; else aHH[tau] = a; }
            }
        }
    }
    const int rbase = (l >> 4) * 4;
#pragma unroll
    for (int tau = 0; tau < 2; tau++) {
        int c = 32 * w + (l & 15) + (tau ? 16 : 0);
        float bz0 = bq[c],       bz1 = bq[N3 + c];
        float br0 = bq[128 + c], br1 = bq[N3 + 128 + c];
        float bh0 = bq[256 + c], bh1 = bq[N3 + 256 + c];
#pragma unroll
        for (int i = 0; i < 4; i++) {
            size_t row = (size_t)(r0 + rbase + i);
            float hold = g_queue[row * DD + c];
            float z = fsig(aZ[tau][i] + bz0 + bz1);
            float r = fsig(aR[tau][i] + br0 + br1);
            float cand = ftanh(aIH[tau][i] + bh0 + r * (aHH[tau][i] + bh1));
            float hn = z * hold + (1.0f - z) * cand;
            g_queue[row * DD + c] = hn;
            if (hn != 0.0f) nzf[rbase + i] = 1;
        }
    }
    __syncthreads();
    if (tid < 16) g_nzq[r0 + tid] = nzf[tid];
}

// ---------- link GRU with LOCAL projection (queue i belongs to link i/3) ----------
__global__ __launch_bounds__(256) void k_link_mfma(const float* __restrict__ bl) {
    __shared__ unsigned short proj[48][128][3];          // fp16 local qs@Wl + bl0
    __shared__ unsigned short sh_hi[16][136], sh_lo[16][136];
    __shared__ int mA[3][16], nzf[16];
    const int tid = threadIdx.x, w = tid >> 6, l = tid & 63;
    const int r0 = blockIdx.x * 16;
    if (tid < 16) nzf[tid] = 0;
    if (tid < 48) {
        int r = tid / 3, j = tid % 3;
        mA[j][r] = g_nzq[3 * (r0 + r) + j];
    }
    const int rbase = (l >> 4) * 4;
    // --- local projection: 3 stages of 16 queue rows each ---
    for (int s = 0; s < 3; s++) {
        int qbase = 3 * r0 + 16 * s;
        for (int idx = tid; idx < 16 * DD; idx += 256) {
            unsigned short hi, lo;
            split_bf(g_queue[(size_t)qbase * DD + idx], hi, lo);
            sh_hi[idx >> 7][idx & 127] = hi; sh_lo[idx >> 7][idx & 127] = lo;
        }
        __syncthreads();
        f32x4 acc[6];
#pragma unroll
        for (int n = 0; n < 6; n++) acc[n] = (f32x4){0.f, 0.f, 0.f, 0.f};
#pragma unroll
        for (int kc = 0; kc < 4; kc++) {
            int kk = kc * 32 + (l >> 4) * 8;
            bf16x8 ah = *reinterpret_cast<const bf16x8*>(&sh_hi[l & 15][kk]);
            bf16x8 al = *reinterpret_cast<const bf16x8*>(&sh_lo[l & 15][kk]);
#pragma unroll
            for (int n = 0; n < 6; n++) {
                int nt = 6 * w + n;
                size_t boff = ((size_t)(nt * 4 + kc)) * FR + (size_t)l * 8;
                bf16x8 bhv = *reinterpret_cast<const bf16x8*>(&g_wlb_hi[boff]);
                bf16x8 blv = *reinterpret_cast<const bf16x8*>(&g_wlb_lo[boff]);
                acc[n] = __builtin_amdgcn_mfma_f32_16x16x32_bf16(ah, bhv, acc[n], 0, 0, 0);
                acc[n] = __builtin_amdgcn_mfma_f32_16x16x32_bf16(al, bhv, acc[n], 0, 0, 0);
                acc[n] = __builtin_amdgcn_mfma_f32_16x16x32_bf16(ah, blv, acc[n], 0, 0, 0);
            }
        }
#pragma unroll
        for (int n = 0; n < 6; n++) {
            int nt = 6 * w + n;
            int gate = nt >> 3, wc = (nt & 7) * 16 + (l & 15);
            float bv = bl[gate * 128 + wc];
#pragma unroll
            for (int i = 0; i < 4; i++)
                proj[16 * s + rbase + i][wc][gate] = f2h(acc[n][i] + bv);
        }
        __syncthreads();
    }
    // --- link GRU: 3 timesteps ---
    const int c0 = 32 * w + (l & 15), c1 = c0 + 16;
    float h0[4], h1[4];
#pragma unroll
    for (int i = 0; i < 4; i++) {
        h0[i] = g_link[(size_t)(r0 + rbase + i) * DD + c0];
        h1[i] = g_link[(size_t)(r0 + rbase + i) * DD + c1];
    }
#pragma unroll
    for (int i = 0; i < 4; i++) {
        unsigned short hi, lo;
        split_bf(h0[i], hi, lo); sh_hi[rbase + i][c0] = hi; sh_lo[rbase + i][c0] = lo;
        split_bf(h1[i], hi, lo); sh_hi[rbase + i][c1] = hi; sh_lo[rbase + i][c1] = lo;
    }
    __syncthreads();
    float bz[2], br[2], bh[2];
    bz[0] = bl[N3 + c0]; bz[1] = bl[N3 + c1];
    br[0] = bl[N3 + 128 + c0]; br[1] = bl[N3 + 128 + c1];
    bh[0] = bl[N3 + 256 + c0]; bh[1] = bl[N3 + 256 + c1];

    for (int t = 0; t < 3; t++) {
        int msk[4];
#pragma unroll
        for (int i = 0; i < 4; i++) msk[i] = mA[t][rbase + i];
        bf16x8 ah[4], al[4];
#pragma unroll
        for (int kc = 0; kc < 4; kc++) {
            ah[kc] = *reinterpret_cast<const bf16x8*>(&sh_hi[l & 15][kc * 32 + (l >> 4) * 8]);
            al[kc] = *reinterpret_cast<const bf16x8*>(&sh_lo[l & 15][kc * 32 + (l >> 4) * 8]);
        }
        f32x4 acc[3][2];
#pragma unroll
        for (int g = 0; g < 3; g++)
#pragma unroll
            for (int tau = 0; tau < 2; tau++) acc[g][tau] = (f32x4){0.f, 0.f, 0.f, 0.f};
#pragma unroll
        for (int kc = 0; kc < 4; kc++) {
#pragma unroll
            for (int g = 0; g < 3; g++) {
#pragma unroll
                for (int tau = 0; tau < 2; tau++) {
                    int nt = g * 8 + 2 * w + tau;
                    size_t boff = ((size_t)(nt * 4 + kc)) * FR + (size_t)l * 8;
                    bf16x8 bhv = *reinterpret_cast<const bf16x8*>(&g_ulb_hi[boff]);
                    bf16x8 blv = *reinterpret_cast<const bf16x8*>(&g_ulb_lo[boff]);
                    acc[g][tau] = __builtin_amdgcn_mfma_f32_16x16x32_bf16(ah[kc], bhv, acc[g][tau], 0, 0, 0);
                    acc[g][tau] = __builtin_amdgcn_mfma_f32_16x16x32_bf16(al[kc], bhv, acc[g][tau], 0, 0, 0);
                    acc[g][tau] = __builtin_amdgcn_mfma_f32_16x16x32_bf16(ah[kc], blv, acc[g][tau], 0, 0, 0);
                }
            }
        }
        __syncthreads();
#pragma unroll
        for (int tau = 0; tau < 2; tau++) {
            int cc = tau ? c1 : c0;
#pragma unroll
            for (int i = 0; i < 4; i++) {
                int qloc = 3 * (rbase + i) + t;
                float q0 = h2f(proj[qloc][cc][0]);
                float q1 = h2f(proj[qloc][cc][1]);
                float q2 = h2f(proj[qloc][cc][2]);
                float zin = acc[0][tau][i] + q0 + bz[tau];
                float rin = acc[1][tau][i] + q1 + br[tau];
                float hold = tau ? h1[i] : h0[i];
                float zv = fsig(zin);
                float rv = fsig(rin);
                float cand = ftanh(q2 + rv * (acc[2][tau][i] + bh[tau]));
                float hn = zv * hold + (1.0f - zv) * cand;
                float hout = msk[i] ? hn : hold;
                if (tau) h1[i] = hout; else h0[i] = hout;
            }
        }
#pragma unroll
        for (int i = 0; i < 4; i++) {
            unsigned short hi, lo;
            split_bf(h0[i], hi, lo); sh_hi[rbase + i][c0] = hi; sh_lo[rbase + i][c0] = lo;
            split_bf(h1[i], hi, lo); sh_hi[rbase + i][c1] = hi; sh_lo[rbase + i][c1] = lo;
        }
        __syncthreads();
    }
#pragma unroll
    for (int i = 0; i < 4; i++) {
        g_link[(size_t)(r0 + rbase + i) * DD + c0] = h0[i];
        g_link[(size_t)(r0 + rbase + i) * DD + c1] = h1[i];
        if (h0[i] != 0.0f || h1[i] != 0.0f) nzf[rbase + i] = 1;
    }
    __syncthreads();
    if (tid < 16) g_nzl[r0 + tid] = nzf[tid];
}

// ---------- readout via MFMA ----------
__global__ __launch_bounds__(256) void k_readout_mfma(const float* __restrict__ b1,
                                                      const float* __restrict__ b2,
                                                      const float* __restrict__ W3,
                                                      const float* __restrict__ b3,
                                                      float* __restrict__ out) {
    __shared__ unsigned short s1_hi[16][136], s1_lo[16][136];
    __shared__ unsigned short r1_hi[16][264], r1_lo[16][264];
    __shared__ float r2f[16][256];
    const int tid = threadIdx.x, w = tid >> 6, l = tid & 63;
    const int r0 = blockIdx.x * 16;
    for (int idx = tid; idx < 16 * DD; idx += 256) {
        unsigned short hi, lo;
        split_bf(g_path[(size_t)r0 * DD + idx], hi, lo);
        s1_hi[idx >> 7][idx & 127] = hi; s1_lo[idx >> 7][idx & 127] = lo;
    }
    __syncthreads();
    const int rbase = (l >> 4) * 4;
    {
        f32x4 acc[4];
#pragma unroll
        for (int n = 0; n < 4; n++) acc[n] = (f32x4){0.f, 0.f, 0.f, 0.f};
#pragma unroll
        for (int kc = 0; kc < 4; kc++) {
            int kk = kc * 32 + (l >> 4) * 8;
            bf16x8 ah = *reinterpret_cast<const bf16x8*>(&s1_hi[l & 15][kk]);
            bf16x8 al = *reinterpret_cast<const bf16x8*>(&s1_lo[l & 15][kk]);
#pragma unroll
            for (int n = 0; n < 4; n++) {
                int nt = 4 * w + n;
                size_t boff = ((size_t)(nt * 4 + kc)) * FR + (size_t)l * 8;
                bf16x8 bhv = *reinterpret_cast<const bf16x8*>(&g_w1b_hi[boff]);
                bf16x8 blv = *reinterpret_cast<const bf16x8*>(&g_w1b_lo[boff]);
                acc[n] = __builtin_amdgcn_mfma_f32_16x16x32_bf16(ah, bhv, acc[n], 0, 0, 0);
                acc[n] = __builtin_amdgcn_mfma_f32_16x16x32_bf16(al, bhv, acc[n], 0, 0, 0);
                acc[n] = __builtin_amdgcn_mfma_f32_16x16x32_bf16(ah, blv, acc[n], 0, 0, 0);
            }
        }
#pragma unroll
        for (int n = 0; n < 4; n++) {
            int col = (4 * w + n) * 16 + (l & 15);
#pragma unroll
            for (int i = 0; i < 4; i++) {
                float v = fmaxf(acc[n][i] + b1[col], 0.f);
                unsigned short hi, lo;
                split_bf(v, hi, lo);
                r1_hi[rbase + i][col] = hi; r1_lo[rbase + i][col] = lo;
            }
        }
    }
    __syncthreads();
    {
        f32x4 acc[4];
#pragma unroll
        for (int n = 0; n < 4; n++) acc[n] = (f32x4){0.f, 0.f, 0.f, 0.f};
#pragma unroll
        for (int kc = 0; kc < 8; kc++) {
            int kk = kc * 32 + (l >> 4) * 8;
            bf16x8 ah = *reinterpret_cast<const bf16x8*>(&r1_hi[l & 15][kk]);
            bf16x8 al = *reinterpret_cast<const bf16x8*>(&r1_lo[l & 15][kk]);
#pragma unroll
            for (int n = 0; n < 4; n++) {
                int nt = 4 * w + n;
                size_t boff = ((size_t)(nt * 8 + kc)) * FR + (size_t)l * 8;
                bf16x8 bhv = *reinterpret_cast<const bf16x8*>(&g_w2b_hi[boff]);
                bf16x8 blv = *reinterpret_cast<const bf16x8*>(&g_w2b_lo[boff]);
                acc[n] = __builtin_amdgcn_mfma_f32_16x16x32_bf16(ah, bhv, acc[n], 0, 0, 0);
                acc[n] = __builtin_amdgcn_mfma_f32_16x16x32_bf16(al, bhv, acc[n], 0, 0, 0);
                acc[n] = __builtin_amdgcn_mfma_f32_16x16x32_bf16(ah, blv, acc[n], 0, 0, 0);
            }
        }
#pragma unroll
        for (int n = 0; n < 4; n++) {
            int col = (4 * w + n) * 16 + (l & 15);
#pragma unroll
            for (int i = 0; i < 4; i++)
                r2f[rbase + i][col] = fmaxf(acc[n][i] + b2[col], 0.f);
        }
    }
    __syncthreads();
    {
        float w3a = W3[l], w3b = W3[l + 64], w3c = W3[l + 128], w3d = W3[l + 192];
#pragma unroll
        for (int rr = 0; rr < 4; rr++) {
            int row = w * 4 + rr;
            float s = r2f[row][l] * w3a + r2f[row][l + 64] * w3b +
                      r2f[row][l + 128] * w3c + r2f[row][l + 192] * w3d;
            for (int off = 32; off > 0; off >>= 1) s += __shfl_down(s, off);
            if (l == 0) out[r0 + row] = s + b3[0];
        }
    }
}

extern "C" void kernel_launch(void* const* d_in, const int* in_sizes, int n_in,
                              void* d_out, int out_size, void* d_ws, size_t ws_size,
                              hipStream_t stream) {
    const float* traffic  = (const float*)d_in[0];
    const float* packets  = (const float*)d_in[1];
    const float* capacity = (const float*)d_in[2];
    const float* weight   = (const float*)d_in[3];
    const int* policy     = (const int*)d_in[4];
    const int* priority   = (const int*)d_in[5];
    const int* path_ids   = (const int*)d_in[6];
    const int* l_q_p      = (const int*)d_in[7];
    const int* l_p_s      = (const int*)d_in[8];
    const int* link_to_path    = (const int*)d_in[9];
    const int* queue_to_path   = (const int*)d_in[10];
    const int* path_to_queue   = (const int*)d_in[11];
    const int* sequence_queues = (const int*)d_in[12];
    const float* Wp  = (const float*)d_in[19];
    const float* Up  = (const float*)d_in[20];
    const float* bp  = (const float*)d_in[21];
    const float* Wl  = (const float*)d_in[22];
    const float* Ul  = (const float*)d_in[23];
    const float* bl  = (const float*)d_in[24];
    const float* Wq  = (const float*)d_in[25];
    const float* Uq  = (const float*)d_in[26];
    const float* bq  = (const float*)d_in[27];
    const float* Wr1 = (const float*)d_in[28];
    const float* br1 = (const float*)d_in[29];
    const float* Wr2 = (const float*)d_in[30];
    const float* br2 = (const float*)d_in[31];
    const float* Wr3 = (const float*)d_in[32];
    const float* br3 = (const float*)d_in[33];
    float* out = (float*)d_out;

    k_init_maps<<<(NE + 255) / 256, 256, 0, stream>>>();
    k_fill_maps<<<(NE + 255) / 256, 256, 0, stream>>>(path_ids, l_q_p, l_p_s, queue_to_path,
                                                      link_to_path, sequence_queues);
    k_scan<<<1, 1024, 0, stream>>>();
    k_fill_csr<<<(NE + 255) / 256, 256, 0, stream>>>(sequence_queues, path_to_queue);
    k_init_states<<<(NP * DD + 255) / 256, 256, 0, stream>>>(traffic, packets, capacity,
                                                             policy, weight, priority);
    k_pack<<<192, 256, 0, stream>>>(0, Up, N3);
    k_pack<<<192, 256, 0, stream>>>(1, Wp, N3);
    k_pack<<<192, 256, 0, stream>>>(2, Wp + 128 * N3, N3);
    k_pack<<<192, 256, 0, stream>>>(3, Wl, N3);
    k_pack<<<192, 256, 0, stream>>>(4, Wq, N3);
    k_pack<<<192, 256, 0, stream>>>(5, Uq, N3);
    k_pack<<<192, 256, 0, stream>>>(6, Ul, N3);
    k_pack<<<128, 256, 0, stream>>>(7, Wr1, 256);
    k_pack<<<256, 256, 0, stream>>>(8, Wr2, 256);
    k_nz<<<NQ / 4, 256, 0, stream>>>(0);
    k_nz<<<NL / 4, 256, 0, stream>>>(1);

    for (int it = 0; it < TT; ++it) {
        k_gemm_mfma<<<NQ / 16 + NL / 16, 256, 0, stream>>>(bp);  // both projections
        k_path<<<NP / 16, 256, 0, stream>>>(bp);
        k_queue_mfma<<<NQ / 16, 256, 0, stream>>>(bq);           // includes CSR qsum
        k_link_mfma<<<NL / 16, 256, 0, stream>>>(bl);            // includes local qs@Wl
    }

    k_readout_mfma<<<NP / 16, 256, 0, stream>>>(br1, br2, Wr3, br3, out);
}

// Round 10
// 1964.779 us; speedup vs baseline: 1.1421x; 1.1421x over previous
//
#include <hip/hip_runtime.h>
#include <hip/hip_bf16.h>
#include <hip/hip_fp16.h>
#include <math.h>

#define NP 20000
#define NL 4000
#define NQ 12000
#define NE 160000
#define DD 128
#define N3 384
#define TT 8
#define FR 512   // 64 lanes * 8 elems per fragment slot

typedef __attribute__((ext_vector_type(8))) short bf16x8;
typedef __attribute__((ext_vector_type(4))) float f32x4;

// ---------- device global scratch ----------
__device__ float g_path [NP * DD];
__device__ float g_link [NL * DD];
__device__ float g_queue[NQ * DD];
__device__ unsigned short g_qgi_h[NQ * N3];   // fp16 queue-side input projection
__device__ unsigned short g_lgi_h[NL * N3];   // fp16 link-side input projection
__device__ float g_psum [NQ * DD];
__device__ int   g_peq  [NE];
__device__ int   g_pel  [NE];
__device__ int   g_counts[NQ];
__device__ int   g_off  [NQ + 1];
__device__ int   g_cur  [NQ];
__device__ int   g_col  [NE];
__device__ int   g_nzq  [NQ];
__device__ int   g_nzl  [NL];
// weight packs, MFMA B-fragment layout: [nt][kc_total][lane=64][j=8], hi/lo split bf16
__device__ unsigned short g_upb_hi[24*4*FR], g_upb_lo[24*4*FR];        // Up
__device__ unsigned short g_wpb_hi[2*24*4*FR], g_wpb_lo[2*24*4*FR];    // Wp (2 halves)
__device__ unsigned short g_wlb_hi[24*4*FR], g_wlb_lo[24*4*FR];        // Wl
__device__ unsigned short g_wuq_hi[24*8*FR], g_wuq_lo[24*8*FR];        // [Wq;Uq] K=256
__device__ unsigned short g_ulb_hi[24*4*FR], g_ulb_lo[24*4*FR];        // Ul
__device__ unsigned short g_w1b_hi[16*4*FR], g_w1b_lo[16*4*FR];        // Wr1
__device__ unsigned short g_w2b_hi[16*8*FR], g_w2b_lo[16*8*FR];        // Wr2

__device__ __forceinline__ float fsig(float x)  { return 1.0f / (1.0f + __expf(-x)); }
__device__ __forceinline__ float ftanh(float x) { return 2.0f / (1.0f + __expf(-2.0f * x)) - 1.0f; }

__device__ __forceinline__ void split_bf(float v, unsigned short& hi, unsigned short& lo) {
    unsigned u = __float_as_uint(v);
    hi = (unsigned short)(u >> 16);
    float lof = v - __uint_as_float(u & 0xFFFF0000u);
    lo = (unsigned short)(__float_as_uint(lof) >> 16);
}
__device__ __forceinline__ unsigned short f2h(float v) {
    __half h = __float2half_rn(v);
    return *reinterpret_cast<unsigned short*>(&h);
}
__device__ __forceinline__ float h2f(unsigned short u) {
    __half h = *reinterpret_cast<__half*>(&u);
    return __half2float(h);
}

// ---------- setup kernels ----------
__global__ void k_init_maps() {
    int i = blockIdx.x * 256 + threadIdx.x;
    if (i < NE) { g_peq[i] = -1; g_pel[i] = -1; }
    if (i < NQ) { g_counts[i] = 0; }
}

__global__ void k_fill_maps(const int* __restrict__ path_ids, const int* __restrict__ l_q_p,
                            const int* __restrict__ l_p_s, const int* __restrict__ queue_to_path,
                            const int* __restrict__ link_to_path, const int* __restrict__ sequence_queues) {
    int i = blockIdx.x * 256 + threadIdx.x;
    if (i < NE) {
        int p = path_ids[i];
        g_peq[p * 8 + l_q_p[i]] = queue_to_path[i];
        g_pel[p * 8 + l_p_s[i]] = link_to_path[i];
        atomicAdd(&g_counts[sequence_queues[i]], 1);
    }
}

__global__ __launch_bounds__(1024) void k_scan() {
    __shared__ int part[1024];
    int tid = threadIdx.x;
    int base = tid * 12;
    int local[12];
    int s = 0;
#pragma unroll
    for (int j = 0; j < 12; j++) {
        int idx = base + j;
        int v = (idx < NQ) ? g_counts[idx] : 0;
        local[j] = s; s += v;
    }
    part[tid] = s;
    __syncthreads();
    for (int off = 1; off < 1024; off <<= 1) {
        int v = (tid >= off) ? part[tid - off] : 0;
        __syncthreads();
        part[tid] += v;
        __syncthreads();
    }
    int pre = (tid > 0) ? part[tid - 1] : 0;
#pragma unroll
    for (int j = 0; j < 12; j++) {
        int idx = base + j;
        if (idx < NQ) { g_off[idx] = pre + local[j]; g_cur[idx] = pre + local[j]; }
    }
    if (tid == 1023) g_off[NQ] = part[1023];
}

__global__ void k_fill_csr(const int* __restrict__ sequence_queues, const int* __restrict__ path_to_queue) {
    int i = blockIdx.x * 256 + threadIdx.x;
    if (i < NE) {
        int q = sequence_queues[i];
        int pos = atomicAdd(&g_cur[q], 1);
        g_col[pos] = path_to_queue[i];
    }
}

__global__ void k_init_states(const float* __restrict__ traffic, const float* __restrict__ packets,
                              const float* __restrict__ capacity, const int* __restrict__ policy,
                              const float* __restrict__ weight, const int* __restrict__ priority) {
    int idx = blockIdx.x * 256 + threadIdx.x;
    if (idx < NP * DD) {
        int p = idx >> 7, d = idx & 127;
        g_path[idx] = (d == 0) ? traffic[p] : (d == 1) ? packets[p] : 0.0f;
    }
    if (idx < NL * DD) {
        int l = idx >> 7, d = idx & 127;
        float v = 0.0f;
        if (d == 0) v = capacity[l];
        else if (d >= 1 && d <= 3) v = (policy[l] == d - 1) ? 1.0f : 0.0f;
        g_link[idx] = v;
    }
    if (idx < NQ * DD) {
        int q = idx >> 7, d = idx & 127;
        float v = 0.0f;
        if (d < 3) v = (priority[q] == d) ? 1.0f : 0.0f;
        else if (d == 3) v = weight[q];
        g_queue[idx] = v;
    }
}

// generic weight pack: W[k][col] -> fragment layout, split bf16 hi/lo
// modes: 0=Up 1=Wp.q 2=Wp.l 3=Wl 4=Wq(kcb0) 5=Uq(kcb4) 6=Ul 7=Wr1 8=Wr2
__global__ void k_pack(int mode, const float* __restrict__ W, int ldn) {
    unsigned short *dhi, *dlo;
    int nt_cnt, kc_cnt, kc_total, kc_base;
    if (mode == 0)      { dhi=g_upb_hi; dlo=g_upb_lo; nt_cnt=24; kc_cnt=4; kc_total=4; kc_base=0; }
    else if (mode == 1) { dhi=g_wpb_hi; dlo=g_wpb_lo; nt_cnt=24; kc_cnt=4; kc_total=4; kc_base=0; }
    else if (mode == 2) { dhi=g_wpb_hi+24*4*FR; dlo=g_wpb_lo+24*4*FR; nt_cnt=24; kc_cnt=4; kc_total=4; kc_base=0; }
    else if (mode == 3) { dhi=g_wlb_hi; dlo=g_wlb_lo; nt_cnt=24; kc_cnt=4; kc_total=4; kc_base=0; }
    else if (mode == 4) { dhi=g_wuq_hi; dlo=g_wuq_lo; nt_cnt=24; kc_cnt=4; kc_total=8; kc_base=0; }
    else if (mode == 5) { dhi=g_wuq_hi; dlo=g_wuq_lo; nt_cnt=24; kc_cnt=4; kc_total=8; kc_base=4; }
    else if (mode == 6) { dhi=g_ulb_hi; dlo=g_ulb_lo; nt_cnt=24; kc_cnt=4; kc_total=4; kc_base=0; }
    else if (mode == 7) { dhi=g_w1b_hi; dlo=g_w1b_lo; nt_cnt=16; kc_cnt=4; kc_total=4; kc_base=0; }
    else                { dhi=g_w2b_hi; dlo=g_w2b_lo; nt_cnt=16; kc_cnt=8; kc_total=8; kc_base=0; }
    int tot = nt_cnt * kc_cnt * FR;
    int idx = blockIdx.x * 256 + threadIdx.x;
    if (idx >= tot) return;
    int j = idx & 7, lane = (idx >> 3) & 63;
    int kc = (idx >> 9) % kc_cnt, nt = idx / (kc_cnt * FR);
    int k = kc * 32 + (lane >> 4) * 8 + j;
    int col = nt * 16 + (lane & 15);
    float v = W[(size_t)k * ldn + col];
    unsigned short hi, lo;
    split_bf(v, hi, lo);
    size_t o = ((size_t)(nt * kc_total + kc_base + kc)) * FR + (size_t)lane * 8 + j;
    dhi[o] = hi; dlo[o] = lo;
}

// initial nonzero flags
__global__ void k_nz(int mode) {
    const float* st = mode ? g_link : g_queue;
    int n = mode ? NL : NQ;
    int* outf = mode ? g_nzl : g_nzq;
    int w = threadIdx.x >> 6, lane = threadIdx.x & 63;
    int row = blockIdx.x * 4 + w;
    if (row < n) {
        const float* r = st + (size_t)row * DD;
        bool nz = (r[lane] != 0.0f) || (r[lane + 64] != 0.0f);
        unsigned long long b = __ballot(nz);
        if (lane == 0) outf[row] = (b != 0ULL) ? 1 : 0;
    }
}

// ---------- MFMA GEMM producing fp16 outputs ----------
// mode 3 (merged path-phase): blocks [0, NQ/16): g_queue@Wp.q + bias -> g_qgi_h
//                             blocks [NQ/16, +NL/16): g_link@Wp.l -> g_lgi_h
// mode 2 (link-phase): g_queue@Wl + bias -> g_qgi_h
__global__ __launch_bounds__(256) void k_gemm_mfma(int mode, const float* __restrict__ bias) {
    const float* A; unsigned short* C; const unsigned short *Bh, *Bl;
    int r0; bool useB;
    if (mode == 2) {
        A = g_queue; C = g_qgi_h; Bh = g_wlb_hi; Bl = g_wlb_lo;
        r0 = blockIdx.x * 16; useB = true;
    } else {
        if (blockIdx.x < NQ / 16) {
            A = g_queue; C = g_qgi_h; Bh = g_wpb_hi; Bl = g_wpb_lo;
            r0 = blockIdx.x * 16; useB = true;
        } else {
            A = g_link; C = g_lgi_h; Bh = g_wpb_hi + 24*4*FR; Bl = g_wpb_lo + 24*4*FR;
            r0 = (blockIdx.x - NQ / 16) * 16; useB = false;
        }
    }
    __shared__ unsigned short as_hi[16][136], as_lo[16][136];
    const int tid = threadIdx.x, w = tid >> 6, l = tid & 63;
    for (int idx = tid; idx < 16 * DD; idx += 256) {
        unsigned short hi, lo;
        split_bf(A[(size_t)r0 * DD + idx], hi, lo);
        as_hi[idx >> 7][idx & 127] = hi; as_lo[idx >> 7][idx & 127] = lo;
    }
    __syncthreads();
    f32x4 acc[6];
#pragma unroll
    for (int n = 0; n < 6; n++) acc[n] = (f32x4){0.f, 0.f, 0.f, 0.f};
#pragma unroll
    for (int kc = 0; kc < 4; kc++) {
        int kk = kc * 32 + (l >> 4) * 8;
        bf16x8 ah = *reinterpret_cast<const bf16x8*>(&as_hi[l & 15][kk]);
        bf16x8 al = *reinterpret_cast<const bf16x8*>(&as_lo[l & 15][kk]);
#pragma unroll
        for (int n = 0; n < 6; n++) {
            int nt = 6 * w + n;
            size_t boff = ((size_t)(nt * 4 + kc)) * FR + (size_t)l * 8;
            bf16x8 bhv = *reinterpret_cast<const bf16x8*>(&Bh[boff]);
            bf16x8 blv = *reinterpret_cast<const bf16x8*>(&Bl[boff]);
            acc[n] = __builtin_amdgcn_mfma_f32_16x16x32_bf16(ah, bhv, acc[n], 0, 0, 0);
            acc[n] = __builtin_amdgcn_mfma_f32_16x16x32_bf16(al, bhv, acc[n], 0, 0, 0);
            acc[n] = __builtin_amdgcn_mfma_f32_16x16x32_bf16(ah, blv, acc[n], 0, 0, 0);
        }
    }
    const int rbase = (l >> 4) * 4;
#pragma unroll
    for (int n = 0; n < 6; n++) {
        int col = (6 * w + n) * 16 + (l & 15);
        float bv = useB ? bias[col] : 0.f;
#pragma unroll
        for (int i = 0; i < 4; i++)
            C[(size_t)(r0 + rbase + i) * N3 + col] = f2h(acc[n][i] + bv);
    }
}

// ---------- fused path GRU: 8 waves, each owns ONE 16-col tile (low reg pressure) ----------
__global__ __launch_bounds__(512) void k_path(const float* __restrict__ bp) {
    __shared__ unsigned short hs_hi[2][16][136];
    __shared__ unsigned short hs_lo[2][16][136];
    __shared__ int qqA[8][16], llA[8][16], mAsh[8][16];
    const int tid = threadIdx.x;
    const int w = tid >> 6, l = tid & 63;
    const int r0 = blockIdx.x * 16;
    if (tid < 128) {
        int r = tid >> 3, t = tid & 7;
        int e = (r0 + r) * 8 + t;
        int qq = g_peq[e], ll = g_pel[e];
        qqA[t][r] = qq; llA[t][r] = ll;
        mAsh[t][r] = (g_nzq[qq] | g_nzl[ll]);
    }
    const int c0 = 16 * w + (l & 15);           // each wave owns one 16-col tile
    const int rbase = (l >> 4) * 4;
    float h0[4];
#pragma unroll
    for (int i = 0; i < 4; i++)
        h0[i] = g_path[(size_t)(r0 + rbase + i) * DD + c0];
#pragma unroll
    for (int i = 0; i < 4; i++) {
        unsigned short hi, lo;
        split_bf(h0[i], hi, lo);
        hs_hi[0][rbase + i][c0] = hi; hs_lo[0][rbase + i][c0] = lo;
    }
    __syncthreads();
    const float bz = bp[N3 + c0], br = bp[N3 + 128 + c0], bh = bp[N3 + 256 + c0];

    for (int t = 0; t < TT; t++) {
        const int cur = t & 1, nxt = cur ^ 1;
        int msk[4];
#pragma unroll
        for (int i = 0; i < 4; i++) msk[i] = mAsh[t][rbase + i];
        // combined gathers: 24 x 2B loads, 12 live floats
        float gz[4], gr[4], gh[4];
#pragma unroll
        for (int i = 0; i < 4; i++) {
            int q = qqA[t][rbase + i], lk = llA[t][rbase + i];
            const unsigned short* qp = g_qgi_h + (size_t)q * N3 + c0;
            const unsigned short* lp = g_lgi_h + (size_t)lk * N3 + c0;
            gz[i] = h2f(qp[0])   + h2f(lp[0]);
            gr[i] = h2f(qp[128]) + h2f(lp[128]);
            gh[i] = h2f(qp[256]) + h2f(lp[256]);
        }
        bf16x8 ah[4], al[4];
#pragma unroll
        for (int kc = 0; kc < 4; kc++) {
            ah[kc] = *reinterpret_cast<const bf16x8*>(&hs_hi[cur][l & 15][kc * 32 + (l >> 4) * 8]);
            al[kc] = *reinterpret_cast<const bf16x8*>(&hs_lo[cur][l & 15][kc * 32 + (l >> 4) * 8]);
        }
        f32x4 acc[3];
#pragma unroll
        for (int g = 0; g < 3; g++) acc[g] = (f32x4){0.f, 0.f, 0.f, 0.f};
#pragma unroll
        for (int kc = 0; kc < 4; kc++) {
#pragma unroll
            for (int g = 0; g < 3; g++) {
                int nt = g * 8 + w;
                size_t boff = ((size_t)(nt * 4 + kc) * 64 + l) * 8;
                bf16x8 bhv = *reinterpret_cast<const bf16x8*>(&g_upb_hi[boff]);
                bf16x8 blv = *reinterpret_cast<const bf16x8*>(&g_upb_lo[boff]);
                acc[g] = __builtin_amdgcn_mfma_f32_16x16x32_bf16(ah[kc], bhv, acc[g], 0, 0, 0);
                acc[g] = __builtin_amdgcn_mfma_f32_16x16x32_bf16(al[kc], bhv, acc[g], 0, 0, 0);
                acc[g] = __builtin_amdgcn_mfma_f32_16x16x32_bf16(ah[kc], blv, acc[g], 0, 0, 0);
            }
        }
        // epilogue: gates, update h, write other LDS buffer; single barrier/timestep
#pragma unroll
        for (int i = 0; i < 4; i++) {
            float zin = acc[0][i] + gz[i] + bz;
            float rin = acc[1][i] + gr[i] + br;
            float zv = fsig(zin);
            float rv = fsig(rin);
            float cand = ftanh(gh[i] + rv * (acc[2][i] + bh));
            float hn = zv * h0[i] + (1.0f - zv) * cand;
            h0[i] = msk[i] ? hn : h0[i];
        }
#pragma unroll
        for (int i = 0; i < 4; i++) {
            unsigned short hi, lo;
            split_bf(h0[i], hi, lo);
            hs_hi[nxt][rbase + i][c0] = hi; hs_lo[nxt][rbase + i][c0] = lo;
        }
        __syncthreads();
    }
#pragma unroll
    for (int i = 0; i < 4; i++)
        g_path[(size_t)(r0 + rbase + i) * DD + c0] = h0[i];
}

// ---------- per-queue segment sum of path states via CSR ----------
__global__ void k_qsum() {
    int w = threadIdx.x >> 6, lane = threadIdx.x & 63;
    int q = blockIdx.x * 4 + w;
    if (q >= NQ) return;
    int s = g_off[q], e = g_off[q + 1];
    float a0 = 0.f, a1 = 0.f;
    for (int i = s; i < e; i++) {
        const float* p = g_path + (size_t)g_col[i] * DD;
        a0 += p[lane]; a1 += p[lane + 64];
    }
    g_psum[(size_t)q * DD + lane] = a0;
    g_psum[(size_t)q * DD + lane + 64] = a1;
}

// ---------- queue GRU via MFMA: K=256 combined [x;h]; nz flags folded in ----------
__global__ __launch_bounds__(256) void k_queue_mfma(const float* __restrict__ bq) {
    __shared__ unsigned short xs_hi[16][136], xs_lo[16][136];
    __shared__ unsigned short hs_hi[16][136], hs_lo[16][136];
    __shared__ int nzf[16];
    const int tid = threadIdx.x, w = tid >> 6, l = tid & 63;
    const int r0 = blockIdx.x * 16;
    if (tid < 16) nzf[tid] = 0;
    for (int idx = tid; idx < 16 * DD; idx += 256) {
        unsigned short hi, lo;
        split_bf(g_psum[(size_t)r0 * DD + idx], hi, lo);
        xs_hi[idx >> 7][idx & 127] = hi; xs_lo[idx >> 7][idx & 127] = lo;
        split_bf(g_queue[(size_t)r0 * DD + idx], hi, lo);
        hs_hi[idx >> 7][idx & 127] = hi; hs_lo[idx >> 7][idx & 127] = lo;
    }
    __syncthreads();
    f32x4 aZ[2], aR[2], aIH[2], aHH[2];
#pragma unroll
    for (int tau = 0; tau < 2; tau++) {
        aZ[tau] = (f32x4){0.f,0.f,0.f,0.f}; aR[tau] = (f32x4){0.f,0.f,0.f,0.f};
        aIH[tau] = (f32x4){0.f,0.f,0.f,0.f}; aHH[tau] = (f32x4){0.f,0.f,0.f,0.f};
    }
#pragma unroll
    for (int kc = 0; kc < 8; kc++) {
        int kk = (kc & 3) * 32 + (l >> 4) * 8;
        bf16x8 ah, al;
        if (kc < 4) {
            ah = *reinterpret_cast<const bf16x8*>(&xs_hi[l & 15][kk]);
            al = *reinterpret_cast<const bf16x8*>(&xs_lo[l & 15][kk]);
        } else {
            ah = *reinterpret_cast<const bf16x8*>(&hs_hi[l & 15][kk]);
            al = *reinterpret_cast<const bf16x8*>(&hs_lo[l & 15][kk]);
        }
#pragma unroll
        for (int g = 0; g < 3; g++) {
#pragma unroll
            for (int tau = 0; tau < 2; tau++) {
                int nt = g * 8 + 2 * w + tau;
                size_t boff = ((size_t)(nt * 8 + kc)) * FR + (size_t)l * 8;
                bf16x8 bhv = *reinterpret_cast<const bf16x8*>(&g_wuq_hi[boff]);
                bf16x8 blv = *reinterpret_cast<const bf16x8*>(&g_wuq_lo[boff]);
                f32x4 a = (g == 0) ? aZ[tau] : (g == 1) ? aR[tau] : (kc < 4 ? aIH[tau] : aHH[tau]);
                a = __builtin_amdgcn_mfma_f32_16x16x32_bf16(ah, bhv, a, 0, 0, 0);
                a = __builtin_amdgcn_mfma_f32_16x16x32_bf16(al, bhv, a, 0, 0, 0);
                a = __builtin_amdgcn_mfma_f32_16x16x32_bf16(ah, blv, a, 0, 0, 0);
                if (g == 0) aZ[tau] = a; else if (g == 1) aR[tau] = a;
                else { if (kc < 4) aIH[tau] = a; else aHH[tau] = a; }
            }
        }
    }
    const int rbase = (l >> 4) * 4;
#pragma unroll
    for (int tau = 0; tau < 2; tau++) {
        int c = 32 * w + (l & 15) + (tau ? 16 : 0);
        float bz0 = bq[c],       bz1 = bq[N3 + c];
        float br0 = bq[128 + c], br1 = bq[N3 + 128 + c];
        float bh0 = bq[256 + c], bh1 = bq[N3 + 256 + c];
#pragma unroll
        for (int i = 0; i < 4; i++) {
            size_t row = (size_t)(r0 + rbase + i);
            float hold = g_queue[row * DD + c];
            float z = fsig(aZ[tau][i] + bz0 + bz1);
            float r = fsig(aR[tau][i] + br0 + br1);
            float cand = ftanh(aIH[tau][i] + bh0 + r * (aHH[tau][i] + bh1));
            float hn = z * hold + (1.0f - z) * cand;
            g_queue[row * DD + c] = hn;
            if (hn != 0.0f) nzf[rbase + i] = 1;
        }
    }
    __syncthreads();
    if (tid < 16) g_nzq[r0 + tid] = nzf[tid];
}

// ---------- link GRU via MFMA: 3 timesteps, fp16 gather, nz flags folded ----------
__global__ __launch_bounds__(256) void k_link_mfma(const float* __restrict__ bl) {
    __shared__ unsigned short hs_hi[16][136], hs_lo[16][136];
    __shared__ int mA[3][16], nzf[16];
    const int tid = threadIdx.x, w = tid >> 6, l = tid & 63;
    const int r0 = blockIdx.x * 16;
    if (tid < 16) nzf[tid] = 0;
    if (tid < 48) {
        int r = tid / 3, j = tid % 3;
        mA[j][r] = g_nzq[3 * (r0 + r) + j];
    }
    const int c0 = 32 * w + (l & 15), c1 = c0 + 16;
    const int rbase = (l >> 4) * 4;
    float h0[4], h1[4];
#pragma unroll
    for (int i = 0; i < 4; i++) {
        h0[i] = g_link[(size_t)(r0 + rbase + i) * DD + c0];
        h1[i] = g_link[(size_t)(r0 + rbase + i) * DD + c1];
    }
#pragma unroll
    for (int i = 0; i < 4; i++) {
        unsigned short hi, lo;
        split_bf(h0[i], hi, lo); hs_hi[rbase + i][c0] = hi; hs_lo[rbase + i][c0] = lo;
        split_bf(h1[i], hi, lo); hs_hi[rbase + i][c1] = hi; hs_lo[rbase + i][c1] = lo;
    }
    __syncthreads();
    float bz[2], br[2], bh[2];
    bz[0] = bl[N3 + c0]; bz[1] = bl[N3 + c1];
    br[0] = bl[N3 + 128 + c0]; br[1] = bl[N3 + 128 + c1];
    bh[0] = bl[N3 + 256 + c0]; bh[1] = bl[N3 + 256 + c1];

    for (int t = 0; t < 3; t++) {
        int msk[4];
#pragma unroll
        for (int i = 0; i < 4; i++) msk[i] = mA[t][rbase + i];
        float gq[2][4][3];
#pragma unroll
        for (int tau = 0; tau < 2; tau++) {
            int cc = tau ? c1 : c0;
#pragma unroll
            for (int i = 0; i < 4; i++) {
                int q = 3 * (r0 + rbase + i) + t;   // queue_to_link = arange: link L owns queues 3L..3L+2
                const unsigned short* qp = g_qgi_h + (size_t)q * N3 + cc;
                gq[tau][i][0] = h2f(qp[0]); gq[tau][i][1] = h2f(qp[128]); gq[tau][i][2] = h2f(qp[256]);
            }
        }
        bf16x8 ah[4], al[4];
#pragma unroll
        for (int kc = 0; kc < 4; kc++) {
            ah[kc] = *reinterpret_cast<const bf16x8*>(&hs_hi[l & 15][kc * 32 + (l >> 4) * 8]);
            al[kc] = *reinterpret_cast<const bf16x8*>(&hs_lo[l & 15][kc * 32 + (l >> 4) * 8]);
        }
        f32x4 acc[3][2];
#pragma unroll
        for (int g = 0; g < 3; g++)
#pragma unroll
            for (int tau = 0; tau < 2; tau++) acc[g][tau] = (f32x4){0.f, 0.f, 0.f, 0.f};
#pragma unroll
        for (int kc = 0; kc < 4; kc++) {
#pragma unroll
            for (int g = 0; g < 3; g++) {
#pragma unroll
                for (int tau = 0; tau < 2; tau++) {
                    int nt = g * 8 + 2 * w + tau;
                    size_t boff = ((size_t)(nt * 4 + kc)) * FR + (size_t)l * 8;
                    bf16x8 bhv = *reinterpret_cast<const bf16x8*>(&g_ulb_hi[boff]);
                    bf16x8 blv = *reinterpret_cast<const bf16x8*>(&g_ulb_lo[boff]);
                    acc[g][tau] = __builtin_amdgcn_mfma_f32_16x16x32_bf16(ah[kc], bhv, acc[g][tau], 0, 0, 0);
                    acc[g][tau] = __builtin_amdgcn_mfma_f32_16x16x32_bf16(al[kc], bhv, acc[g][tau], 0, 0, 0);
                    acc[g][tau] = __builtin_amdgcn_mfma_f32_16x16x32_bf16(ah[kc], blv, acc[g][tau], 0, 0, 0);
                }
            }
        }
        __syncthreads();
#pragma unroll
        for (int tau = 0; tau < 2; tau++) {
#pragma unroll
            for (int i = 0; i < 4; i++) {
                float zin = acc[0][tau][i] + gq[tau][i][0] + bz[tau];
                float rin = acc[1][tau][i] + gq[tau][i][1] + br[tau];
                float hold = tau ? h1[i] : h0[i];
                float zv = fsig(zin);
                float rv = fsig(rin);
                float cand = ftanh(gq[tau][i][2] + rv * (acc[2][tau][i] + bh[tau]));
                float hn = zv * hold + (1.0f - zv) * cand;
                float hout = msk[i] ? hn : hold;
                if (tau) h1[i] = hout; else h0[i] = hout;
            }
        }
#pragma unroll
        for (int i = 0; i < 4; i++) {
            unsigned short hi, lo;
            split_bf(h0[i], hi, lo); hs_hi[rbase + i][c0] = hi; hs_lo[rbase + i][c0] = lo;
            split_bf(h1[i], hi, lo); hs_hi[rbase + i][c1] = hi; hs_lo[rbase + i][c1] = lo;
        }
        __syncthreads();
    }
#pragma unroll
    for (int i = 0; i < 4; i++) {
        g_link[(size_t)(r0 + rbase + i) * DD + c0] = h0[i];
        g_link[(size_t)(r0 + rbase + i) * DD + c1] = h1[i];
        if (h0[i] != 0.0f || h1[i] != 0.0f) nzf[rbase + i] = 1;
    }
    __syncthreads();
    if (tid < 16) g_nzl[r0 + tid] = nzf[tid];
}

// ---------- readout via MFMA ----------
__global__ __launch_bounds__(256) void k_readout_mfma(const float* __restrict__ b1,
                                                      const float* __restrict__ b2,
                                                      const float* __restrict__ W3,
                                                      const float* __restrict__ b3,
                                                      float* __restrict__ out) {
    __shared__ unsigned short s1_hi[16][136], s1_lo[16][136];
    __shared__ unsigned short r1_hi[16][264], r1_lo[16][264];
    __shared__ float r2f[16][256];
    const int tid = threadIdx.x, w = tid >> 6, l = tid & 63;
    const int r0 = blockIdx.x * 16;
    for (int idx = tid; idx < 16 * DD; idx += 256) {
        unsigned short hi, lo;
        split_bf(g_path[(size_t)r0 * DD + idx], hi, lo);
        s1_hi[idx >> 7][idx & 127] = hi; s1_lo[idx >> 7][idx & 127] = lo;
    }
    __syncthreads();
    const int rbase = (l >> 4) * 4;
    {
        f32x4 acc[4];
#pragma unroll
        for (int n = 0; n < 4; n++) acc[n] = (f32x4){0.f, 0.f, 0.f, 0.f};
#pragma unroll
        for (int kc = 0; kc < 4; kc++) {
            int kk = kc * 32 + (l >> 4) * 8;
            bf16x8 ah = *reinterpret_cast<const bf16x8*>(&s1_hi[l & 15][kk]);
            bf16x8 al = *reinterpret_cast<const bf16x8*>(&s1_lo[l & 15][kk]);
#pragma unroll
            for (int n = 0; n < 4; n++) {
                int nt = 4 * w + n;
                size_t boff = ((size_t)(nt * 4 + kc)) * FR + (size_t)l * 8;
                bf16x8 bhv = *reinterpret_cast<const bf16x8*>(&g_w1b_hi[boff]);
                bf16x8 blv = *reinterpret_cast<const bf16x8*>(&g_w1b_lo[boff]);
                acc[n] = __builtin_amdgcn_mfma_f32_16x16x32_bf16(ah, bhv, acc[n], 0, 0, 0);
                acc[n] = __builtin_amdgcn_mfma_f32_16x16x32_bf16(al, bhv, acc[n], 0, 0, 0);
                acc[n] = __builtin_amdgcn_mfma_f32_16x16x32_bf16(ah, blv, acc[n], 0, 0, 0);
            }
        }
#pragma unroll
        for (int n = 0; n < 4; n++) {
            int col = (4 * w + n) * 16 + (l & 15);
#pragma unroll
            for (int i = 0; i < 4; i++) {
                float v = fmaxf(acc[n][i] + b1[col], 0.f);
                unsigned short hi, lo;
                split_bf(v, hi, lo);
                r1_hi[rbase + i][col] = hi; r1_lo[rbase + i][col] = lo;
            }
        }
    }
    __syncthreads();
    {
        f32x4 acc[4];
#pragma unroll
        for (int n = 0; n < 4; n++) acc[n] = (f32x4){0.f, 0.f, 0.f, 0.f};
#pragma unroll
        for (int kc = 0; kc < 8; kc++) {
            int kk = kc * 32 + (l >> 4) * 8;
            bf16x8 ah = *reinterpret_cast<const bf16x8*>(&r1_hi[l & 15][kk]);
            bf16x8 al = *reinterpret_cast<const bf16x8*>(&r1_lo[l & 15][kk]);
#pragma unroll
            for (int n = 0; n < 4; n++) {
                int nt = 4 * w + n;
                size_t boff = ((size_t)(nt * 8 + kc)) * FR + (size_t)l * 8;
                bf16x8 bhv = *reinterpret_cast<const bf16x8*>(&g_w2b_hi[boff]);
                bf16x8 blv = *reinterpret_cast<const bf16x8*>(&g_w2b_lo[boff]);
                acc[n] = __builtin_amdgcn_mfma_f32_16x16x32_bf16(ah, bhv, acc[n], 0, 0, 0);
                acc[n] = __builtin_amdgcn_mfma_f32_16x16x32_bf16(al, bhv, acc[n], 0, 0, 0);
                acc[n] = __builtin_amdgcn_mfma_f32_16x16x32_bf16(ah, blv, acc[n], 0, 0, 0);
            }
        }
#pragma unroll
        for (int n = 0; n < 4; n++) {
            int col = (4 * w + n) * 16 + (l & 15);
#pragma unroll
            for (int i = 0; i < 4; i++)
                r2f[rbase + i][col] = fmaxf(acc[n][i] + b2[col], 0.f);
        }
    }
    __syncthreads();
    {
        float w3a = W3[l], w3b = W3[l + 64], w3c = W3[l + 128], w3d = W3[l + 192];
#pragma unroll
        for (int rr = 0; rr < 4; rr++) {
            int row = w * 4 + rr;
            float s = r2f[row][l] * w3a + r2f[row][l + 64] * w3b +
                      r2f[row][l + 128] * w3c + r2f[row][l + 192] * w3d;
            for (int off = 32; off > 0; off >>= 1) s += __shfl_down(s, off);
            if (l == 0) out[r0 + row] = s + b3[0];
        }
    }
}

extern "C" void kernel_launch(void* const* d_in, const int* in_sizes, int n_in,
                              void* d_out, int out_size, void* d_ws, size_t ws_size,
                              hipStream_t stream) {
    const float* traffic  = (const float*)d_in[0];
    const float* packets  = (const float*)d_in[1];
    const float* capacity = (const float*)d_in[2];
    const float* weight   = (const float*)d_in[3];
    const int* policy     = (const int*)d_in[4];
    const int* priority   = (const int*)d_in[5];
    const int* path_ids   = (const int*)d_in[6];
    const int* l_q_p      = (const int*)d_in[7];
    const int* l_p_s      = (const int*)d_in[8];
    const int* link_to_path    = (const int*)d_in[9];
    const int* queue_to_path   = (const int*)d_in[10];
    const int* path_to_queue   = (const int*)d_in[11];
    const int* sequence_queues = (const int*)d_in[12];
    const float* Wp  = (const float*)d_in[19];
    const float* Up  = (const float*)d_in[20];
    const float* bp  = (const float*)d_in[21];
    const float* Wl  = (const float*)d_in[22];
    const float* Ul  = (const float*)d_in[23];
    const float* bl  = (const float*)d_in[24];
    const float* Wq  = (const float*)d_in[25];
    const float* Uq  = (const float*)d_in[26];
    const float* bq  = (const float*)d_in[27];
    const float* Wr1 = (const float*)d_in[28];
    const float* br1 = (const float*)d_in[29];
    const float* Wr2 = (const float*)d_in[30];
    const float* br2 = (const float*)d_in[31];
    const float* Wr3 = (const float*)d_in[32];
    const float* br3 = (const float*)d_in[33];
    float* out = (float*)d_out;

    k_init_maps<<<(NE + 255) / 256, 256, 0, stream>>>();
    k_fill_maps<<<(NE + 255) / 256, 256, 0, stream>>>(path_ids, l_q_p, l_p_s, queue_to_path,
                                                      link_to_path, sequence_queues);
    k_scan<<<1, 1024, 0, stream>>>();
    k_fill_csr<<<(NE + 255) / 256, 256, 0, stream>>>(sequence_queues, path_to_queue);
    k_init_states<<<(NP * DD + 255) / 256, 256, 0, stream>>>(traffic, packets, capacity,
                                                             policy, weight, priority);
    k_pack<<<192, 256, 0, stream>>>(0, Up, N3);
    k_pack<<<192, 256, 0, stream>>>(1, Wp, N3);
    k_pack<<<192, 256, 0, stream>>>(2, Wp + 128 * N3, N3);
    k_pack<<<192, 256, 0, stream>>>(3, Wl, N3);
    k_pack<<<192, 256, 0, stream>>>(4, Wq, N3);
    k_pack<<<192, 256, 0, stream>>>(5, Uq, N3);
    k_pack<<<192, 256, 0, stream>>>(6, Ul, N3);
    k_pack<<<128, 256, 0, stream>>>(7, Wr1, 256);
    k_pack<<<256, 256, 0, stream>>>(8, Wr2, 256);
    k_nz<<<NQ / 4, 256, 0, stream>>>(0);
    k_nz<<<NL / 4, 256, 0, stream>>>(1);

    for (int it = 0; it < TT; ++it) {
        // path phase: merged projections then fused recurrent MFMA steps (8-wave blocks)
        k_gemm_mfma<<<NQ / 16 + NL / 16, 256, 0, stream>>>(3, bp);
        k_path<<<NP / 16, 512, 0, stream>>>(bp);
        // queue phase (separate qsum for max TLP; nzq folded into k_queue_mfma)
        k_qsum<<<NQ / 4, 256, 0, stream>>>();
        k_queue_mfma<<<NQ / 16, 256, 0, stream>>>(bq);
        // link phase (projection as separate wide GEMM; nzl folded into k_link_mfma)
        k_gemm_mfma<<<NQ / 16, 256, 0, stream>>>(2, bl);
        k_link_mfma<<<NL / 16, 256, 0, stream>>>(bl);
    }

    k_readout_mfma<<<NP / 16, 256, 0, stream>>>(br1, br2, Wr3, br3, out);
}

// Round 12
// 1665.208 us; speedup vs baseline: 1.3476x; 1.1799x over previous
//
#include <hip/hip_runtime.h>
#include <hip/hip_bf16.h>
#include <hip/hip_fp16.h>
#include <math.h>

#define NP 20000
#define NL 4000
#define NQ 12000
#define NE 160000
#define DD 128
#define N3 384
#define TT 8
#define FR 512   // 64 lanes * 8 elems per fragment slot

typedef __attribute__((ext_vector_type(8))) short bf16x8;
typedef __attribute__((ext_vector_type(4))) float f32x4;

// ---------- device global scratch ----------
__device__ float g_path [NP * DD];
__device__ float g_link [NL * DD];
__device__ float g_queue[NQ * DD];
__device__ unsigned short g_qgi_h[NQ * N3];   // fp16 queue-side input projection
__device__ unsigned short g_lgi_h[NL * N3];   // fp16 link-side input projection
__device__ float g_psum [NQ * DD];
__device__ int   g_peq  [NE];
__device__ int   g_pel  [NE];
__device__ int   g_counts[NQ];
__device__ int   g_off  [NQ + 1];
__device__ int   g_cur  [NQ];
__device__ int   g_col  [NE];
__device__ int   g_nzq  [NQ];
__device__ int   g_nzl  [NL];
// weight packs, MFMA B-fragment layout: [nt][kc_total][lane=64][j=8], hi/lo split bf16
__device__ unsigned short g_upb_hi[24*4*FR], g_upb_lo[24*4*FR];        // Up
__device__ unsigned short g_wpb_hi[2*24*4*FR], g_wpb_lo[2*24*4*FR];    // Wp (2 halves)
__device__ unsigned short g_wlb_hi[24*4*FR], g_wlb_lo[24*4*FR];        // Wl
__device__ unsigned short g_wuq_hi[24*8*FR], g_wuq_lo[24*8*FR];        // [Wq;Uq] K=256
__device__ unsigned short g_ulb_hi[24*4*FR], g_ulb_lo[24*4*FR];        // Ul
__device__ unsigned short g_w1b_hi[16*4*FR], g_w1b_lo[16*4*FR];        // Wr1
__device__ unsigned short g_w2b_hi[16*8*FR], g_w2b_lo[16*8*FR];        // Wr2

__device__ __forceinline__ float fsig(float x)  { return 1.0f / (1.0f + __expf(-x)); }
__device__ __forceinline__ float ftanh(float x) { return 2.0f / (1.0f + __expf(-2.0f * x)) - 1.0f; }

__device__ __forceinline__ void split_bf(float v, unsigned short& hi, unsigned short& lo) {
    unsigned u = __float_as_uint(v);
    hi = (unsigned short)(u >> 16);
    float lof = v - __uint_as_float(u & 0xFFFF0000u);
    lo = (unsigned short)(__float_as_uint(lof) >> 16);
}
__device__ __forceinline__ unsigned short f2h(float v) {
    __half h = __float2half_rn(v);
    return *reinterpret_cast<unsigned short*>(&h);
}
__device__ __forceinline__ float h2f(unsigned short u) {
    __half h = *reinterpret_cast<__half*>(&u);
    return __half2float(h);
}

// ---------- setup kernels ----------
__global__ void k_init_maps() {
    int i = blockIdx.x * 256 + threadIdx.x;
    if (i < NE) { g_peq[i] = -1; g_pel[i] = -1; }
    if (i < NQ) { g_counts[i] = 0; }
}

__global__ void k_fill_maps(const int* __restrict__ path_ids, const int* __restrict__ l_q_p,
                            const int* __restrict__ l_p_s, const int* __restrict__ queue_to_path,
                            const int* __restrict__ link_to_path, const int* __restrict__ sequence_queues) {
    int i = blockIdx.x * 256 + threadIdx.x;
    if (i < NE) {
        int p = path_ids[i];
        g_peq[p * 8 + l_q_p[i]] = queue_to_path[i];
        g_pel[p * 8 + l_p_s[i]] = link_to_path[i];
        atomicAdd(&g_counts[sequence_queues[i]], 1);
    }
}

__global__ __launch_bounds__(1024) void k_scan() {
    __shared__ int part[1024];
    int tid = threadIdx.x;
    int base = tid * 12;
    int local[12];
    int s = 0;
#pragma unroll
    for (int j = 0; j < 12; j++) {
        int idx = base + j;
        int v = (idx < NQ) ? g_counts[idx] : 0;
        local[j] = s; s += v;
    }
    part[tid] = s;
    __syncthreads();
    for (int off = 1; off < 1024; off <<= 1) {
        int v = (tid >= off) ? part[tid - off] : 0;
        __syncthreads();
        part[tid] += v;
        __syncthreads();
    }
    int pre = (tid > 0) ? part[tid - 1] : 0;
#pragma unroll
    for (int j = 0; j < 12; j++) {
        int idx = base + j;
        if (idx < NQ) { g_off[idx] = pre + local[j]; g_cur[idx] = pre + local[j]; }
    }
    if (tid == 1023) g_off[NQ] = part[1023];
}

__global__ void k_fill_csr(const int* __restrict__ sequence_queues, const int* __restrict__ path_to_queue) {
    int i = blockIdx.x * 256 + threadIdx.x;
    if (i < NE) {
        int q = sequence_queues[i];
        int pos = atomicAdd(&g_cur[q], 1);
        g_col[pos] = path_to_queue[i];
    }
}

__global__ void k_init_states(const float* __restrict__ traffic, const float* __restrict__ packets,
                              const float* __restrict__ capacity, const int* __restrict__ policy,
                              const float* __restrict__ weight, const int* __restrict__ priority) {
    int idx = blockIdx.x * 256 + threadIdx.x;
    if (idx < NP * DD) {
        int p = idx >> 7, d = idx & 127;
        g_path[idx] = (d == 0) ? traffic[p] : (d == 1) ? packets[p] : 0.0f;
    }
    if (idx < NL * DD) {
        int l = idx >> 7, d = idx & 127;
        float v = 0.0f;
        if (d == 0) v = capacity[l];
        else if (d >= 1 && d <= 3) v = (policy[l] == d - 1) ? 1.0f : 0.0f;
        g_link[idx] = v;
    }
    if (idx < NQ * DD) {
        int q = idx >> 7, d = idx & 127;
        float v = 0.0f;
        if (d < 3) v = (priority[q] == d) ? 1.0f : 0.0f;
        else if (d == 3) v = weight[q];
        g_queue[idx] = v;
    }
}

// generic weight pack: W[k][col] -> fragment layout, split bf16 hi/lo
// modes: 0=Up 1=Wp.q 2=Wp.l 3=Wl 4=Wq(kcb0) 5=Uq(kcb4) 6=Ul 7=Wr1 8=Wr2
__global__ void k_pack(int mode, const float* __restrict__ W, int ldn) {
    unsigned short *dhi, *dlo;
    int nt_cnt, kc_cnt, kc_total, kc_base;
    if (mode == 0)      { dhi=g_upb_hi; dlo=g_upb_lo; nt_cnt=24; kc_cnt=4; kc_total=4; kc_base=0; }
    else if (mode == 1) { dhi=g_wpb_hi; dlo=g_wpb_lo; nt_cnt=24; kc_cnt=4; kc_total=4; kc_base=0; }
    else if (mode == 2) { dhi=g_wpb_hi+24*4*FR; dlo=g_wpb_lo+24*4*FR; nt_cnt=24; kc_cnt=4; kc_total=4; kc_base=0; }
    else if (mode == 3) { dhi=g_wlb_hi; dlo=g_wlb_lo; nt_cnt=24; kc_cnt=4; kc_total=4; kc_base=0; }
    else if (mode == 4) { dhi=g_wuq_hi; dlo=g_wuq_lo; nt_cnt=24; kc_cnt=4; kc_total=8; kc_base=0; }
    else if (mode == 5) { dhi=g_wuq_hi; dlo=g_wuq_lo; nt_cnt=24; kc_cnt=4; kc_total=8; kc_base=4; }
    else if (mode == 6) { dhi=g_ulb_hi; dlo=g_ulb_lo; nt_cnt=24; kc_cnt=4; kc_total=4; kc_base=0; }
    else if (mode == 7) { dhi=g_w1b_hi; dlo=g_w1b_lo; nt_cnt=16; kc_cnt=4; kc_total=4; kc_base=0; }
    else                { dhi=g_w2b_hi; dlo=g_w2b_lo; nt_cnt=16; kc_cnt=8; kc_total=8; kc_base=0; }
    int tot = nt_cnt * kc_cnt * FR;
    int idx = blockIdx.x * 256 + threadIdx.x;
    if (idx >= tot) return;
    int j = idx & 7, lane = (idx >> 3) & 63;
    int kc = (idx >> 9) % kc_cnt, nt = idx / (kc_cnt * FR);
    int k = kc * 32 + (lane >> 4) * 8 + j;
    int col = nt * 16 + (lane & 15);
    float v = W[(size_t)k * ldn + col];
    unsigned short hi, lo;
    split_bf(v, hi, lo);
    size_t o = ((size_t)(nt * kc_total + kc_base + kc)) * FR + (size_t)lane * 8 + j;
    dhi[o] = hi; dlo[o] = lo;
}

// initial nonzero flags
__global__ void k_nz(int mode) {
    const float* st = mode ? g_link : g_queue;
    int n = mode ? NL : NQ;
    int* outf = mode ? g_nzl : g_nzq;
    int w = threadIdx.x >> 6, lane = threadIdx.x & 63;
    int row = blockIdx.x * 4 + w;
    if (row < n) {
        const float* r = st + (size_t)row * DD;
        bool nz = (r[lane] != 0.0f) || (r[lane + 64] != 0.0f);
        unsigned long long b = __ballot(nz);
        if (lane == 0) outf[row] = (b != 0ULL) ? 1 : 0;
    }
}

// ---------- MFMA GEMM producing fp16 outputs ----------
// mode 3 (merged path-phase): blocks [0, NQ/16): g_queue@Wp.q + bias -> g_qgi_h
//                             blocks [NQ/16, +NL/16): g_link@Wp.l -> g_lgi_h
// mode 2 (link-phase): g_queue@Wl + bias -> g_qgi_h
__global__ __launch_bounds__(256) void k_gemm_mfma(int mode, const float* __restrict__ bias) {
    const float* A; unsigned short* C; const unsigned short *Bh, *Bl;
    int r0; bool useB;
    if (mode == 2) {
        A = g_queue; C = g_qgi_h; Bh = g_wlb_hi; Bl = g_wlb_lo;
        r0 = blockIdx.x * 16; useB = true;
    } else {
        if (blockIdx.x < NQ / 16) {
            A = g_queue; C = g_qgi_h; Bh = g_wpb_hi; Bl = g_wpb_lo;
            r0 = blockIdx.x * 16; useB = true;
        } else {
            A = g_link; C = g_lgi_h; Bh = g_wpb_hi + 24*4*FR; Bl = g_wpb_lo + 24*4*FR;
            r0 = (blockIdx.x - NQ / 16) * 16; useB = false;
        }
    }
    __shared__ unsigned short as_hi[16][136], as_lo[16][136];
    const int tid = threadIdx.x, w = tid >> 6, l = tid & 63;
    for (int idx = tid; idx < 16 * DD; idx += 256) {
        unsigned short hi, lo;
        split_bf(A[(size_t)r0 * DD + idx], hi, lo);
        as_hi[idx >> 7][idx & 127] = hi; as_lo[idx >> 7][idx & 127] = lo;
    }
    __syncthreads();
    f32x4 acc[6];
#pragma unroll
    for (int n = 0; n < 6; n++) acc[n] = (f32x4){0.f, 0.f, 0.f, 0.f};
#pragma unroll
    for (int kc = 0; kc < 4; kc++) {
        int kk = kc * 32 + (l >> 4) * 8;
        bf16x8 ah = *reinterpret_cast<const bf16x8*>(&as_hi[l & 15][kk]);
        bf16x8 al = *reinterpret_cast<const bf16x8*>(&as_lo[l & 15][kk]);
#pragma unroll
        for (int n = 0; n < 6; n++) {
            int nt = 6 * w + n;
            size_t boff = ((size_t)(nt * 4 + kc)) * FR + (size_t)l * 8;
            bf16x8 bhv = *reinterpret_cast<const bf16x8*>(&Bh[boff]);
            bf16x8 blv = *reinterpret_cast<const bf16x8*>(&Bl[boff]);
            acc[n] = __builtin_amdgcn_mfma_f32_16x16x32_bf16(ah, bhv, acc[n], 0, 0, 0);
            acc[n] = __builtin_amdgcn_mfma_f32_16x16x32_bf16(al, bhv, acc[n], 0, 0, 0);
            acc[n] = __builtin_amdgcn_mfma_f32_16x16x32_bf16(ah, blv, acc[n], 0, 0, 0);
        }
    }
    const int rbase = (l >> 4) * 4;
#pragma unroll
    for (int n = 0; n < 6; n++) {
        int col = (6 * w + n) * 16 + (l & 15);
        float bv = useB ? bias[col] : 0.f;
#pragma unroll
        for (int i = 0; i < 4; i++)
            C[(size_t)(r0 + rbase + i) * N3 + col] = f2h(acc[n][i] + bv);
    }
}

// ---------- fused path GRU: 8 waves, ONE 16-col tile each, B-fragments hoisted to regs ----------
__global__ __launch_bounds__(512, 2) void k_path(const float* __restrict__ bp) {
    __shared__ unsigned short hs_hi[2][16][136];
    __shared__ unsigned short hs_lo[2][16][136];
    __shared__ int qqA[8][16], llA[8][16], mAsh[8][16];
    const int tid = threadIdx.x;
    const int w = tid >> 6, l = tid & 63;
    const int r0 = blockIdx.x * 16;
    if (tid < 128) {
        int r = tid >> 3, t = tid & 7;
        int e = (r0 + r) * 8 + t;
        int qq = g_peq[e], ll = g_pel[e];
        qqA[t][r] = qq; llA[t][r] = ll;
        mAsh[t][r] = (g_nzq[qq] | g_nzl[ll]);
    }
    const int c0 = 16 * w + (l & 15);           // each wave owns one 16-col tile
    const int rbase = (l >> 4) * 4;
    // ---- hoist loop-invariant B fragments into registers (12 pairs = 96 VGPRs) ----
    bf16x8 Bh[12], Bl[12];
#pragma unroll
    for (int kc = 0; kc < 4; kc++) {
#pragma unroll
        for (int g = 0; g < 3; g++) {
            int nt = g * 8 + w;
            size_t boff = ((size_t)(nt * 4 + kc) * 64 + l) * 8;
            Bh[kc * 3 + g] = *reinterpret_cast<const bf16x8*>(&g_upb_hi[boff]);
            Bl[kc * 3 + g] = *reinterpret_cast<const bf16x8*>(&g_upb_lo[boff]);
        }
    }
    float h0[4];
#pragma unroll
    for (int i = 0; i < 4; i++)
        h0[i] = g_path[(size_t)(r0 + rbase + i) * DD + c0];
#pragma unroll
    for (int i = 0; i < 4; i++) {
        unsigned short hi, lo;
        split_bf(h0[i], hi, lo);
        hs_hi[0][rbase + i][c0] = hi; hs_lo[0][rbase + i][c0] = lo;
    }
    __syncthreads();
    const float bz = bp[N3 + c0], br = bp[N3 + 128 + c0], bh = bp[N3 + 256 + c0];

    for (int t = 0; t < TT; t++) {
        const int cur = t & 1, nxt = cur ^ 1;
        int msk[4];
#pragma unroll
        for (int i = 0; i < 4; i++) msk[i] = mAsh[t][rbase + i];
        // combined gathers: 24 x 2B loads, 12 live floats
        float gz[4], gr[4], gh[4];
#pragma unroll
        for (int i = 0; i < 4; i++) {
            int q = qqA[t][rbase + i], lk = llA[t][rbase + i];
            const unsigned short* qp = g_qgi_h + (size_t)q * N3 + c0;
            const unsigned short* lp = g_lgi_h + (size_t)lk * N3 + c0;
            gz[i] = h2f(qp[0])   + h2f(lp[0]);
            gr[i] = h2f(qp[128]) + h2f(lp[128]);
            gh[i] = h2f(qp[256]) + h2f(lp[256]);
        }
        bf16x8 ah[4], al[4];
#pragma unroll
        for (int kc = 0; kc < 4; kc++) {
            ah[kc] = *reinterpret_cast<const bf16x8*>(&hs_hi[cur][l & 15][kc * 32 + (l >> 4) * 8]);
            al[kc] = *reinterpret_cast<const bf16x8*>(&hs_lo[cur][l & 15][kc * 32 + (l >> 4) * 8]);
        }
        f32x4 acc[3];
#pragma unroll
        for (int g = 0; g < 3; g++) acc[g] = (f32x4){0.f, 0.f, 0.f, 0.f};
#pragma unroll
        for (int kc = 0; kc < 4; kc++) {
#pragma unroll
            for (int g = 0; g < 3; g++) {
                bf16x8 bhv = Bh[kc * 3 + g];
                bf16x8 blv = Bl[kc * 3 + g];
                acc[g] = __builtin_amdgcn_mfma_f32_16x16x32_bf16(ah[kc], bhv, acc[g], 0, 0, 0);
                acc[g] = __builtin_amdgcn_mfma_f32_16x16x32_bf16(al[kc], bhv, acc[g], 0, 0, 0);
                acc[g] = __builtin_amdgcn_mfma_f32_16x16x32_bf16(ah[kc], blv, acc[g], 0, 0, 0);
            }
        }
        // epilogue: gates, update h, write other LDS buffer; single barrier/timestep
#pragma unroll
        for (int i = 0; i < 4; i++) {
            float zin = acc[0][i] + gz[i] + bz;
            float rin = acc[1][i] + gr[i] + br;
            float zv = fsig(zin);
            float rv = fsig(rin);
            float cand = ftanh(gh[i] + rv * (acc[2][i] + bh));
            float hn = zv * h0[i] + (1.0f - zv) * cand;
            h0[i] = msk[i] ? hn : h0[i];
        }
#pragma unroll
        for (int i = 0; i < 4; i++) {
            unsigned short hi, lo;
            split_bf(h0[i], hi, lo);
            hs_hi[nxt][rbase + i][c0] = hi; hs_lo[nxt][rbase + i][c0] = lo;
        }
        __syncthreads();
    }
#pragma unroll
    for (int i = 0; i < 4; i++)
        g_path[(size_t)(r0 + rbase + i) * DD + c0] = h0[i];
}

// ---------- per-queue segment sum of path states via CSR ----------
__global__ void k_qsum() {
    int w = threadIdx.x >> 6, lane = threadIdx.x & 63;
    int q = blockIdx.x * 4 + w;
    if (q >= NQ) return;
    int s = g_off[q], e = g_off[q + 1];
    float a0 = 0.f, a1 = 0.f;
    for (int i = s; i < e; i++) {
        const float* p = g_path + (size_t)g_col[i] * DD;
        a0 += p[lane]; a1 += p[lane + 64];
    }
    g_psum[(size_t)q * DD + lane] = a0;
    g_psum[(size_t)q * DD + lane + 64] = a1;
}

// ---------- queue GRU via MFMA: K=256 combined [x;h]; nz flags folded in ----------
__global__ __launch_bounds__(256) void k_queue_mfma(const float* __restrict__ bq) {
    __shared__ unsigned short xs_hi[16][136], xs_lo[16][136];
    __shared__ unsigned short hs_hi[16][136], hs_lo[16][136];
    __shared__ int nzf[16];
    const int tid = threadIdx.x, w = tid >> 6, l = tid & 63;
    const int r0 = blockIdx.x * 16;
    if (tid < 16) nzf[tid] = 0;
    for (int idx = tid; idx < 16 * DD; idx += 256) {
        unsigned short hi, lo;
        split_bf(g_psum[(size_t)r0 * DD + idx], hi, lo);
        xs_hi[idx >> 7][idx & 127] = hi; xs_lo[idx >> 7][idx & 127] = lo;
        split_bf(g_queue[(size_t)r0 * DD + idx], hi, lo);
        hs_hi[idx >> 7][idx & 127] = hi; hs_lo[idx >> 7][idx & 127] = lo;
    }
    __syncthreads();
    f32x4 aZ[2], aR[2], aIH[2], aHH[2];
#pragma unroll
    for (int tau = 0; tau < 2; tau++) {
        aZ[tau] = (f32x4){0.f,0.f,0.f,0.f}; aR[tau] = (f32x4){0.f,0.f,0.f,0.f};
        aIH[tau] = (f32x4){0.f,0.f,0.f,0.f}; aHH[tau] = (f32x4){0.f,0.f,0.f,0.f};
    }
#pragma unroll
    for (int kc = 0; kc < 8; kc++) {
        int kk = (kc & 3) * 32 + (l >> 4) * 8;
        bf16x8 ah, al;
        if (kc < 4) {
            ah = *reinterpret_cast<const bf16x8*>(&xs_hi[l & 15][kk]);
            al = *reinterpret_cast<const bf16x8*>(&xs_lo[l & 15][kk]);
        } else {
            ah = *reinterpret_cast<const bf16x8*>(&hs_hi[l & 15][kk]);
            al = *reinterpret_cast<const bf16x8*>(&hs_lo[l & 15][kk]);
        }
#pragma unroll
        for (int g = 0; g < 3; g++) {
#pragma unroll
            for (int tau = 0; tau < 2; tau++) {
                int nt = g * 8 + 2 * w + tau;
                size_t boff = ((size_t)(nt * 8 + kc)) * FR + (size_t)l * 8;
                bf16x8 bhv = *reinterpret_cast<const bf16x8*>(&g_wuq_hi[boff]);
                bf16x8 blv = *reinterpret_cast<const bf16x8*>(&g_wuq_lo[boff]);
                f32x4 a = (g == 0) ? aZ[tau] : (g == 1) ? aR[tau] : (kc < 4 ? aIH[tau] : aHH[tau]);
                a = __builtin_amdgcn_mfma_f32_16x16x32_bf16(ah, bhv, a, 0, 0, 0);
                a = __builtin_amdgcn_mfma_f32_16x16x32_bf16(al, bhv, a, 0, 0, 0);
                a = __builtin_amdgcn_mfma_f32_16x16x32_bf16(ah, blv, a, 0, 0, 0);
                if (g == 0) aZ[tau] = a; else if (g == 1) aR[tau] = a;
                else { if (kc < 4) aIH[tau] = a; else aHH[tau] = a; }
            }
        }
    }
    const int rbase = (l >> 4) * 4;
#pragma unroll
    for (int tau = 0; tau < 2; tau++) {
        int c = 32 * w + (l & 15) + (tau ? 16 : 0);
        float bz0 = bq[c],       bz1 = bq[N3 + c];
        float br0 = bq[128 + c], br1 = bq[N3 + 128 + c];
        float bh0 = bq[256 + c], bh1 = bq[N3 + 256 + c];
#pragma unroll
        for (int i = 0; i < 4; i++) {
            size_t row = (size_t)(r0 + rbase + i);
            float hold = g_queue[row * DD + c];
            float z = fsig(aZ[tau][i] + bz0 + bz1);
            float r = fsig(aR[tau][i] + br0 + br1);
            float cand = ftanh(aIH[tau][i] + bh0 + r * (aHH[tau][i] + bh1));
            float hn = z * hold + (1.0f - z) * cand;
            g_queue[row * DD + c] = hn;
            if (hn != 0.0f) nzf[rbase + i] = 1;
        }
    }
    __syncthreads();
    if (tid < 16) g_nzq[r0 + tid] = nzf[tid];
}

// ---------- link GRU via MFMA: 3 timesteps, fp16 gather, nz flags folded ----------
__global__ __launch_bounds__(256) void k_link_mfma(const float* __restrict__ bl) {
    __shared__ unsigned short hs_hi[16][136], hs_lo[16][136];
    __shared__ int mA[3][16], nzf[16];
    const int tid = threadIdx.x, w = tid >> 6, l = tid & 63;
    const int r0 = blockIdx.x * 16;
    if (tid < 16) nzf[tid] = 0;
    if (tid < 48) {
        int r = tid / 3, j = tid % 3;
        mA[j][r] = g_nzq[3 * (r0 + r) + j];
    }
    const int c0 = 32 * w + (l & 15), c1 = c0 + 16;
    const int rbase = (l >> 4) * 4;
    float h0[4], h1[4];
#pragma unroll
    for (int i = 0; i < 4; i++) {
        h0[i] = g_link[(size_t)(r0 + rbase + i) * DD + c0];
        h1[i] = g_link[(size_t)(r0 + rbase + i) * DD + c1];
    }
#pragma unroll
    for (int i = 0; i < 4; i++) {
        unsigned short hi, lo;
        split_bf(h0[i], hi, lo); hs_hi[rbase + i][c0] = hi; hs_lo[rbase + i][c0] = lo;
        split_bf(h1[i], hi, lo); hs_hi[rbase + i][c1] = hi; hs_lo[rbase + i][c1] = lo;
    }
    __syncthreads();
    float bz[2], br[2], bh[2];
    bz[0] = bl[N3 + c0]; bz[1] = bl[N3 + c1];
    br[0] = bl[N3 + 128 + c0]; br[1] = bl[N3 + 128 + c1];
    bh[0] = bl[N3 + 256 + c0]; bh[1] = bl[N3 + 256 + c1];

    for (int t = 0; t < 3; t++) {
        int msk[4];
#pragma unroll
        for (int i = 0; i < 4; i++) msk[i] = mA[t][rbase + i];
        float gq[2][4][3];
#pragma unroll
        for (int tau = 0; tau < 2; tau++) {
            int cc = tau ? c1 : c0;
#pragma unroll
            for (int i = 0; i < 4; i++) {
                int q = 3 * (r0 + rbase + i) + t;   // queue_to_link = arange: link L owns queues 3L..3L+2
                const unsigned short* qp = g_qgi_h + (size_t)q * N3 + cc;
                gq[tau][i][0] = h2f(qp[0]); gq[tau][i][1] = h2f(qp[128]); gq[tau][i][2] = h2f(qp[256]);
            }
        }
        bf16x8 ah[4], al[4];
#pragma unroll
        for (int kc = 0; kc < 4; kc++) {
            ah[kc] = *reinterpret_cast<const bf16x8*>(&hs_hi[l & 15][kc * 32 + (l >> 4) * 8]);
            al[kc] = *reinterpret_cast<const bf16x8*>(&hs_lo[l & 15][kc * 32 + (l >> 4) * 8]);
        }
        f32x4 acc[3][2];
#pragma unroll
        for (int g = 0; g < 3; g++)
#pragma unroll
            for (int tau = 0; tau < 2; tau++) acc[g][tau] = (f32x4){0.f, 0.f, 0.f, 0.f};
#pragma unroll
        for (int kc = 0; kc < 4; kc++) {
#pragma unroll
            for (int g = 0; g < 3; g++) {
#pragma unroll
                for (int tau = 0; tau < 2; tau++) {
                    int nt = g * 8 + 2 * w + tau;
                    size_t boff = ((size_t)(nt * 4 + kc)) * FR + (size_t)l * 8;
                    bf16x8 bhv = *reinterpret_cast<const bf16x8*>(&g_ulb_hi[boff]);
                    bf16x8 blv = *reinterpret_cast<const bf16x8*>(&g_ulb_lo[boff]);
                    acc[g][tau] = __builtin_amdgcn_mfma_f32_16x16x32_bf16(ah[kc], bhv, acc[g][tau], 0, 0, 0);
                    acc[g][tau] = __builtin_amdgcn_mfma_f32_16x16x32_bf16(al[kc], bhv, acc[g][tau], 0, 0, 0);
                    acc[g][tau] = __builtin_amdgcn_mfma_f32_16x16x32_bf16(ah[kc], blv, acc[g][tau], 0, 0, 0);
                }
            }
        }
        __syncthreads();
#pragma unroll
        for (int tau = 0; tau < 2; tau++) {
#pragma unroll
            for (int i = 0; i < 4; i++) {
                float zin = acc[0][tau][i] + gq[tau][i][0] + bz[tau];
                float rin = acc[1][tau][i] + gq[tau][i][1] + br[tau];
                float hold = tau ? h1[i] : h0[i];
                float zv = fsig(zin);
                float rv = fsig(rin);
                float cand = ftanh(gq[tau][i][2] + rv * (acc[2][tau][i] + bh[tau]));
                float hn = zv * hold + (1.0f - zv) * cand;
                float hout = msk[i] ? hn : hold;
                if (tau) h1[i] = hout; else h0[i] = hout;
            }
        }
#pragma unroll
        for (int i = 0; i < 4; i++) {
            unsigned short hi, lo;
            split_bf(h0[i], hi, lo); hs_hi[rbase + i][c0] = hi; hs_lo[rbase + i][c0] = lo;
            split_bf(h1[i], hi, lo); hs_hi[rbase + i][c1] = hi; hs_lo[rbase + i][c1] = lo;
        }
        __syncthreads();
    }
#pragma unroll
    for (int i = 0; i < 4; i++) {
        g_link[(size_t)(r0 + rbase + i) * DD + c0] = h0[i];
        g_link[(size_t)(r0 + rbase + i) * DD + c1] = h1[i];
        if (h0[i] != 0.0f || h1[i] != 0.0f) nzf[rbase + i] = 1;
    }
    __syncthreads();
    if (tid < 16) g_nzl[r0 + tid] = nzf[tid];
}

// ---------- readout via MFMA ----------
__global__ __launch_bounds__(256) void k_readout_mfma(const float* __restrict__ b1,
                                                      const float* __restrict__ b2,
                                                      const float* __restrict__ W3,
                                                      const float* __restrict__ b3,
                                                      float* __restrict__ out) {
    __shared__ unsigned short s1_hi[16][136], s1_lo[16][136];
    __shared__ unsigned short r1_hi[16][264], r1_lo[16][264];
    __shared__ float r2f[16][256];
    const int tid = threadIdx.x, w = tid >> 6, l = tid & 63;
    const int r0 = blockIdx.x * 16;
    for (int idx = tid; idx < 16 * DD; idx += 256) {
        unsigned short hi, lo;
        split_bf(g_path[(size_t)r0 * DD + idx], hi, lo);
        s1_hi[idx >> 7][idx & 127] = hi; s1_lo[idx >> 7][idx & 127] = lo;
    }
    __syncthreads();
    const int rbase = (l >> 4) * 4;
    {
        f32x4 acc[4];
#pragma unroll
        for (int n = 0; n < 4; n++) acc[n] = (f32x4){0.f, 0.f, 0.f, 0.f};
#pragma unroll
        for (int kc = 0; kc < 4; kc++) {
            int kk = kc * 32 + (l >> 4) * 8;
            bf16x8 ah = *reinterpret_cast<const bf16x8*>(&s1_hi[l & 15][kk]);
            bf16x8 al = *reinterpret_cast<const bf16x8*>(&s1_lo[l & 15][kk]);
#pragma unroll
            for (int n = 0; n < 4; n++) {
                int nt = 4 * w + n;
                size_t boff = ((size_t)(nt * 4 + kc)) * FR + (size_t)l * 8;
                bf16x8 bhv = *reinterpret_cast<const bf16x8*>(&g_w1b_hi[boff]);
                bf16x8 blv = *reinterpret_cast<const bf16x8*>(&g_w1b_lo[boff]);
                acc[n] = __builtin_amdgcn_mfma_f32_16x16x32_bf16(ah, bhv, acc[n], 0, 0, 0);
                acc[n] = __builtin_amdgcn_mfma_f32_16x16x32_bf16(al, bhv, acc[n], 0, 0, 0);
                acc[n] = __builtin_amdgcn_mfma_f32_16x16x32_bf16(ah, blv, acc[n], 0, 0, 0);
            }
        }
#pragma unroll
        for (int n = 0; n < 4; n++) {
            int col = (4 * w + n) * 16 + (l & 15);
#pragma unroll
            for (int i = 0; i < 4; i++) {
                float v = fmaxf(acc[n][i] + b1[col], 0.f);
                unsigned short hi, lo;
                split_bf(v, hi, lo);
                r1_hi[rbase + i][col] = hi; r1_lo[rbase + i][col] = lo;
            }
        }
    }
    __syncthreads();
    {
        f32x4 acc[4];
#pragma unroll
        for (int n = 0; n < 4; n++) acc[n] = (f32x4){0.f, 0.f, 0.f, 0.f};
#pragma unroll
        for (int kc = 0; kc < 8; kc++) {
            int kk = kc * 32 + (l >> 4) * 8;
            bf16x8 ah = *reinterpret_cast<const bf16x8*>(&r1_hi[l & 15][kk]);
            bf16x8 al = *reinterpret_cast<const bf16x8*>(&r1_lo[l & 15][kk]);
#pragma unroll
            for (int n = 0; n < 4; n++) {
                int nt = 4 * w + n;
                size_t boff = ((size_t)(nt * 8 + kc)) * FR + (size_t)l * 8;
                bf16x8 bhv = *reinterpret_cast<const bf16x8*>(&g_w2b_hi[boff]);
                bf16x8 blv = *reinterpret_cast<const bf16x8*>(&g_w2b_lo[boff]);
                acc[n] = __builtin_amdgcn_mfma_f32_16x16x32_bf16(ah, bhv, acc[n], 0, 0, 0);
                acc[n] = __builtin_amdgcn_mfma_f32_16x16x32_bf16(al, bhv, acc[n], 0, 0, 0);
                acc[n] = __builtin_amdgcn_mfma_f32_16x16x32_bf16(ah, blv, acc[n], 0, 0, 0);
            }
        }
#pragma unroll
        for (int n = 0; n < 4; n++) {
            int col = (4 * w + n) * 16 + (l & 15);
#pragma unroll
            for (int i = 0; i < 4; i++)
                r2f[rbase + i][col] = fmaxf(acc[n][i] + b2[col], 0.f);
        }
    }
    __syncthreads();
    {
        float w3a = W3[l], w3b = W3[l + 64], w3c = W3[l + 128], w3d = W3[l + 192];
#pragma unroll
        for (int rr = 0; rr < 4; rr++) {
            int row = w * 4 + rr;
            float s = r2f[row][l] * w3a + r2f[row][l + 64] * w3b +
                      r2f[row][l + 128] * w3c + r2f[row][l + 192] * w3d;
            for (int off = 32; off > 0; off >>= 1) s += __shfl_down(s, off);
            if (l == 0) out[r0 + row] = s + b3[0];
        }
    }
}

extern "C" void kernel_launch(void* const* d_in, const int* in_sizes, int n_in,
                              void* d_out, int out_size, void* d_ws, size_t ws_size,
                              hipStream_t stream) {
    const float* traffic  = (const float*)d_in[0];
    const float* packets  = (const float*)d_in[1];
    const float* capacity = (const float*)d_in[2];
    const float* weight   = (const float*)d_in[3];
    const int* policy     = (const int*)d_in[4];
    const int* priority   = (const int*)d_in[5];
    const int* path_ids   = (const int*)d_in[6];
    const int* l_q_p      = (const int*)d_in[7];
    const int* l_p_s      = (const int*)d_in[8];
    const int* link_to_path    = (const int*)d_in[9];
    const int* queue_to_path   = (const int*)d_in[10];
    const int* path_to_queue   = (const int*)d_in[11];
    const int* sequence_queues = (const int*)d_in[12];
    const float* Wp  = (const float*)d_in[19];
    const float* Up  = (const float*)d_in[20];
    const float* bp  = (const float*)d_in[21];
    const float* Wl  = (const float*)d_in[22];
    const float* Ul  = (const float*)d_in[23];
    const float* bl  = (const float*)d_in[24];
    const float* Wq  = (const float*)d_in[25];
    const float* Uq  = (const float*)d_in[26];
    const float* bq  = (const float*)d_in[27];
    const float* Wr1 = (const float*)d_in[28];
    const float* br1 = (const float*)d_in[29];
    const float* Wr2 = (const float*)d_in[30];
    const float* br2 = (const float*)d_in[31];
    const float* Wr3 = (const float*)d_in[32];
    const float* br3 = (const float*)d_in[33];
    float* out = (float*)d_out;

    k_init_maps<<<(NE + 255) / 256, 256, 0, stream>>>();
    k_fill_maps<<<(NE + 255) / 256, 256, 0, stream>>>(path_ids, l_q_p, l_p_s, queue_to_path,
                                                      link_to_path, sequence_queues);
    k_scan<<<1, 1024, 0, stream>>>();
    k_fill_csr<<<(NE + 255) / 256, 256, 0, stream>>>(sequence_queues, path_to_queue);
    k_init_states<<<(NP * DD + 255) / 256, 256, 0, stream>>>(traffic, packets, capacity,
                                                             policy, weight, priority);
    k_pack<<<192, 256, 0, stream>>>(0, Up, N3);
    k_pack<<<192, 256, 0, stream>>>(1, Wp, N3);
    k_pack<<<192, 256, 0, stream>>>(2, Wp + 128 * N3, N3);
    k_pack<<<192, 256, 0, stream>>>(3, Wl, N3);
    k_pack<<<192, 256, 0, stream>>>(4, Wq, N3);
    k_pack<<<192, 256, 0, stream>>>(5, Uq, N3);
    k_pack<<<192, 256, 0, stream>>>(6, Ul, N3);
    k_pack<<<128, 256, 0, stream>>>(7, Wr1, 256);
    k_pack<<<256, 256, 0, stream>>>(8, Wr2, 256);
    k_nz<<<NQ / 4, 256, 0, stream>>>(0);
    k_nz<<<NL / 4, 256, 0, stream>>>(1);

    for (int it = 0; it < TT; ++it) {
        // path phase: merged projections then fused recurrent MFMA steps (8-wave blocks)
        k_gemm_mfma<<<NQ / 16 + NL / 16, 256, 0, stream>>>(3, bp);
        k_path<<<NP / 16, 512, 0, stream>>>(bp);
        // queue phase (separate qsum for max TLP; nzq folded into k_queue_mfma)
        k_qsum<<<NQ / 4, 256, 0, stream>>>();
        k_queue_mfma<<<NQ / 16, 256, 0, stream>>>(bq);
        // link phase (projection as separate wide GEMM; nzl folded into k_link_mfma)
        k_gemm_mfma<<<NQ / 16, 256, 0, stream>>>(2, bl);
        k_link_mfma<<<NL / 16, 256, 0, stream>>>(bl);
    }

    k_readout_mfma<<<NP / 16, 256, 0, stream>>>(br1, br2, Wr3, br3, out);
}

// Round 13
// 1597.194 us; speedup vs baseline: 1.4050x; 1.0426x over previous
//
#include <hip/hip_runtime.h>
#include <hip/hip_bf16.h>
#include <hip/hip_fp16.h>
#include <math.h>

#define NP 20000
#define NL 4000
#define NQ 12000
#define NE 160000
#define DD 128
#define N3 384
#define TT 8
#define FR 512   // 64 lanes * 8 elems per fragment slot

typedef __attribute__((ext_vector_type(8))) short bf16x8;
typedef __attribute__((ext_vector_type(4))) float f32x4;

// ---------- device global scratch ----------
__device__ float g_path [NP * DD];
__device__ float g_link [NL * DD];
__device__ float g_queue[NQ * DD];
__device__ unsigned short g_qgi_h[NQ * N3];   // fp16 queue-side input projection
__device__ unsigned short g_lgi_h[NL * N3];   // fp16 link-side input projection
__device__ float g_psum [NQ * DD];
__device__ int   g_peq  [NE];
__device__ int   g_pel  [NE];
__device__ int   g_counts[NQ];
__device__ int   g_off  [NQ + 1];
__device__ int   g_cur  [NQ];
__device__ int   g_col  [NE];
__device__ int   g_nzq  [NQ];
__device__ int   g_nzl  [NL];
// weight packs, MFMA B-fragment layout: [nt][kc_total][lane=64][j=8], hi/lo split bf16
__device__ unsigned short g_upb_hi[24*4*FR], g_upb_lo[24*4*FR];        // Up
__device__ unsigned short g_wpb_hi[2*24*4*FR], g_wpb_lo[2*24*4*FR];    // Wp (2 halves)
__device__ unsigned short g_wlb_hi[24*4*FR], g_wlb_lo[24*4*FR];        // Wl
__device__ unsigned short g_wuq_hi[24*8*FR], g_wuq_lo[24*8*FR];        // [Wq;Uq] K=256
__device__ unsigned short g_ulb_hi[24*4*FR], g_ulb_lo[24*4*FR];        // Ul
__device__ unsigned short g_w1b_hi[16*4*FR], g_w1b_lo[16*4*FR];        // Wr1
__device__ unsigned short g_w2b_hi[16*8*FR], g_w2b_lo[16*8*FR];        // Wr2

__device__ __forceinline__ float fsig(float x)  { return 1.0f / (1.0f + __expf(-x)); }
__device__ __forceinline__ float ftanh(float x) { return 2.0f / (1.0f + __expf(-2.0f * x)) - 1.0f; }

__device__ __forceinline__ void split_bf(float v, unsigned short& hi, unsigned short& lo) {
    unsigned u = __float_as_uint(v);
    hi = (unsigned short)(u >> 16);
    float lof = v - __uint_as_float(u & 0xFFFF0000u);
    lo = (unsigned short)(__float_as_uint(lof) >> 16);
}
__device__ __forceinline__ unsigned short f2h(float v) {
    __half h = __float2half_rn(v);
    return *reinterpret_cast<unsigned short*>(&h);
}
__device__ __forceinline__ float h2f(unsigned short u) {
    __half h = *reinterpret_cast<__half*>(&u);
    return __half2float(h);
}

// ---------- setup kernels ----------
__global__ void k_init_maps() {
    int i = blockIdx.x * 256 + threadIdx.x;
    if (i < NE) { g_peq[i] = -1; g_pel[i] = -1; }
    if (i < NQ) { g_counts[i] = 0; }
}

__global__ void k_fill_maps(const int* __restrict__ path_ids, const int* __restrict__ l_q_p,
                            const int* __restrict__ l_p_s, const int* __restrict__ queue_to_path,
                            const int* __restrict__ link_to_path, const int* __restrict__ sequence_queues) {
    int i = blockIdx.x * 256 + threadIdx.x;
    if (i < NE) {
        int p = path_ids[i];
        g_peq[p * 8 + l_q_p[i]] = queue_to_path[i];
        g_pel[p * 8 + l_p_s[i]] = link_to_path[i];
        atomicAdd(&g_counts[sequence_queues[i]], 1);
    }
}

__global__ __launch_bounds__(1024) void k_scan() {
    __shared__ int part[1024];
    int tid = threadIdx.x;
    int base = tid * 12;
    int local[12];
    int s = 0;
#pragma unroll
    for (int j = 0; j < 12; j++) {
        int idx = base + j;
        int v = (idx < NQ) ? g_counts[idx] : 0;
        local[j] = s; s += v;
    }
    part[tid] = s;
    __syncthreads();
    for (int off = 1; off < 1024; off <<= 1) {
        int v = (tid >= off) ? part[tid - off] : 0;
        __syncthreads();
        part[tid] += v;
        __syncthreads();
    }
    int pre = (tid > 0) ? part[tid - 1] : 0;
#pragma unroll
    for (int j = 0; j < 12; j++) {
        int idx = base + j;
        if (idx < NQ) { g_off[idx] = pre + local[j]; g_cur[idx] = pre + local[j]; }
    }
    if (tid == 1023) g_off[NQ] = part[1023];
}

__global__ void k_fill_csr(const int* __restrict__ sequence_queues, const int* __restrict__ path_to_queue) {
    int i = blockIdx.x * 256 + threadIdx.x;
    if (i < NE) {
        int q = sequence_queues[i];
        int pos = atomicAdd(&g_cur[q], 1);
        g_col[pos] = path_to_queue[i];
    }
}

__global__ void k_init_states(const float* __restrict__ traffic, const float* __restrict__ packets,
                              const float* __restrict__ capacity, const int* __restrict__ policy,
                              const float* __restrict__ weight, const int* __restrict__ priority) {
    int idx = blockIdx.x * 256 + threadIdx.x;
    if (idx < NP * DD) {
        int p = idx >> 7, d = idx & 127;
        g_path[idx] = (d == 0) ? traffic[p] : (d == 1) ? packets[p] : 0.0f;
    }
    if (idx < NL * DD) {
        int l = idx >> 7, d = idx & 127;
        float v = 0.0f;
        if (d == 0) v = capacity[l];
        else if (d >= 1 && d <= 3) v = (policy[l] == d - 1) ? 1.0f : 0.0f;
        g_link[idx] = v;
    }
    if (idx < NQ * DD) {
        int q = idx >> 7, d = idx & 127;
        float v = 0.0f;
        if (d < 3) v = (priority[q] == d) ? 1.0f : 0.0f;
        else if (d == 3) v = weight[q];
        g_queue[idx] = v;
    }
}

// generic weight pack: W[k][col] -> fragment layout, split bf16 hi/lo
// modes: 0=Up 1=Wp.q 2=Wp.l 3=Wl 4=Wq(kcb0) 5=Uq(kcb4) 6=Ul 7=Wr1 8=Wr2
__global__ void k_pack(int mode, const float* __restrict__ W, int ldn) {
    unsigned short *dhi, *dlo;
    int nt_cnt, kc_cnt, kc_total, kc_base;
    if (mode == 0)      { dhi=g_upb_hi; dlo=g_upb_lo; nt_cnt=24; kc_cnt=4; kc_total=4; kc_base=0; }
    else if (mode == 1) { dhi=g_wpb_hi; dlo=g_wpb_lo; nt_cnt=24; kc_cnt=4; kc_total=4; kc_base=0; }
    else if (mode == 2) { dhi=g_wpb_hi+24*4*FR; dlo=g_wpb_lo+24*4*FR; nt_cnt=24; kc_cnt=4; kc_total=4; kc_base=0; }
    else if (mode == 3) { dhi=g_wlb_hi; dlo=g_wlb_lo; nt_cnt=24; kc_cnt=4; kc_total=4; kc_base=0; }
    else if (mode == 4) { dhi=g_wuq_hi; dlo=g_wuq_lo; nt_cnt=24; kc_cnt=4; kc_total=8; kc_base=0; }
    else if (mode == 5) { dhi=g_wuq_hi; dlo=g_wuq_lo; nt_cnt=24; kc_cnt=4; kc_total=8; kc_base=4; }
    else if (mode == 6) { dhi=g_ulb_hi; dlo=g_ulb_lo; nt_cnt=24; kc_cnt=4; kc_total=4; kc_base=0; }
    else if (mode == 7) { dhi=g_w1b_hi; dlo=g_w1b_lo; nt_cnt=16; kc_cnt=4; kc_total=4; kc_base=0; }
    else                { dhi=g_w2b_hi; dlo=g_w2b_lo; nt_cnt=16; kc_cnt=8; kc_total=8; kc_base=0; }
    int tot = nt_cnt * kc_cnt * FR;
    int idx = blockIdx.x * 256 + threadIdx.x;
    if (idx >= tot) return;
    int j = idx & 7, lane = (idx >> 3) & 63;
    int kc = (idx >> 9) % kc_cnt, nt = idx / (kc_cnt * FR);
    int k = kc * 32 + (lane >> 4) * 8 + j;
    int col = nt * 16 + (lane & 15);
    float v = W[(size_t)k * ldn + col];
    unsigned short hi, lo;
    split_bf(v, hi, lo);
    size_t o = ((size_t)(nt * kc_total + kc_base + kc)) * FR + (size_t)lane * 8 + j;
    dhi[o] = hi; dlo[o] = lo;
}

// initial nonzero flags
__global__ void k_nz(int mode) {
    const float* st = mode ? g_link : g_queue;
    int n = mode ? NL : NQ;
    int* outf = mode ? g_nzl : g_nzq;
    int w = threadIdx.x >> 6, lane = threadIdx.x & 63;
    int row = blockIdx.x * 4 + w;
    if (row < n) {
        const float* r = st + (size_t)row * DD;
        bool nz = (r[lane] != 0.0f) || (r[lane + 64] != 0.0f);
        unsigned long long b = __ballot(nz);
        if (lane == 0) outf[row] = (b != 0ULL) ? 1 : 0;
    }
}

// ---------- MFMA GEMM producing fp16 outputs ----------
// mode 3 (merged path-phase): blocks [0, NQ/16): g_queue@Wp.q + bias -> g_qgi_h
//                             blocks [NQ/16, +NL/16): g_link@Wp.l -> g_lgi_h
// mode 2 (link-phase): g_queue@Wl + bias -> g_qgi_h
__global__ __launch_bounds__(256) void k_gemm_mfma(int mode, const float* __restrict__ bias) {
    const float* A; unsigned short* C; const unsigned short *Bh, *Bl;
    int r0; bool useB;
    if (mode == 2) {
        A = g_queue; C = g_qgi_h; Bh = g_wlb_hi; Bl = g_wlb_lo;
        r0 = blockIdx.x * 16; useB = true;
    } else {
        if (blockIdx.x < NQ / 16) {
            A = g_queue; C = g_qgi_h; Bh = g_wpb_hi; Bl = g_wpb_lo;
            r0 = blockIdx.x * 16; useB = true;
        } else {
            A = g_link; C = g_lgi_h; Bh = g_wpb_hi + 24*4*FR; Bl = g_wpb_lo + 24*4*FR;
            r0 = (blockIdx.x - NQ / 16) * 16; useB = false;
        }
    }
    __shared__ unsigned short as_hi[16][136], as_lo[16][136];
    const int tid = threadIdx.x, w = tid >> 6, l = tid & 63;
    for (int idx = tid; idx < 16 * DD; idx += 256) {
        unsigned short hi, lo;
        split_bf(A[(size_t)r0 * DD + idx], hi, lo);
        as_hi[idx >> 7][idx & 127] = hi; as_lo[idx >> 7][idx & 127] = lo;
    }
    __syncthreads();
    f32x4 acc[6];
#pragma unroll
    for (int n = 0; n < 6; n++) acc[n] = (f32x4){0.f, 0.f, 0.f, 0.f};
#pragma unroll
    for (int kc = 0; kc < 4; kc++) {
        int kk = kc * 32 + (l >> 4) * 8;
        bf16x8 ah = *reinterpret_cast<const bf16x8*>(&as_hi[l & 15][kk]);
        bf16x8 al = *reinterpret_cast<const bf16x8*>(&as_lo[l & 15][kk]);
#pragma unroll
        for (int n = 0; n < 6; n++) {
            int nt = 6 * w + n;
            size_t boff = ((size_t)(nt * 4 + kc)) * FR + (size_t)l * 8;
            bf16x8 bhv = *reinterpret_cast<const bf16x8*>(&Bh[boff]);
            bf16x8 blv = *reinterpret_cast<const bf16x8*>(&Bl[boff]);
            acc[n] = __builtin_amdgcn_mfma_f32_16x16x32_bf16(ah, bhv, acc[n], 0, 0, 0);
            acc[n] = __builtin_amdgcn_mfma_f32_16x16x32_bf16(al, bhv, acc[n], 0, 0, 0);
            acc[n] = __builtin_amdgcn_mfma_f32_16x16x32_bf16(ah, blv, acc[n], 0, 0, 0);
        }
    }
    const int rbase = (l >> 4) * 4;
#pragma unroll
    for (int n = 0; n < 6; n++) {
        int col = (6 * w + n) * 16 + (l & 15);
        float bv = useB ? bias[col] : 0.f;
#pragma unroll
        for (int i = 0; i < 4; i++)
            C[(size_t)(r0 + rbase + i) * N3 + col] = f2h(acc[n][i] + bv);
    }
}

// ---------- fused path GRU: 8 waves, one 16-col tile each, B in regs, gather prefetch ----------
__global__ __launch_bounds__(512, 2) void k_path(const float* __restrict__ bp) {
    __shared__ unsigned short hs_hi[2][16][136];
    __shared__ unsigned short hs_lo[2][16][136];
    __shared__ int qqA[8][16], llA[8][16], mAsh[8][16];
    const int tid = threadIdx.x;
    const int w = tid >> 6, l = tid & 63;
    const int r0 = blockIdx.x * 16;
    if (tid < 128) {
        int r = tid >> 3, t = tid & 7;
        int e = (r0 + r) * 8 + t;
        int qq = g_peq[e], ll = g_pel[e];
        qqA[t][r] = qq; llA[t][r] = ll;
        mAsh[t][r] = (g_nzq[qq] | g_nzl[ll]);
    }
    const int c0 = 16 * w + (l & 15);           // each wave owns one 16-col tile
    const int rbase = (l >> 4) * 4;
    // ---- hoist loop-invariant B fragments into registers (12 pairs = 96 VGPRs) ----
    bf16x8 Bh[12], Bl[12];
#pragma unroll
    for (int kc = 0; kc < 4; kc++) {
#pragma unroll
        for (int g = 0; g < 3; g++) {
            int nt = g * 8 + w;
            size_t boff = ((size_t)(nt * 4 + kc) * 64 + l) * 8;
            Bh[kc * 3 + g] = *reinterpret_cast<const bf16x8*>(&g_upb_hi[boff]);
            Bl[kc * 3 + g] = *reinterpret_cast<const bf16x8*>(&g_upb_lo[boff]);
        }
    }
    float h0[4];
#pragma unroll
    for (int i = 0; i < 4; i++)
        h0[i] = g_path[(size_t)(r0 + rbase + i) * DD + c0];
#pragma unroll
    for (int i = 0; i < 4; i++) {
        unsigned short hi, lo;
        split_bf(h0[i], hi, lo);
        hs_hi[0][rbase + i][c0] = hi; hs_lo[0][rbase + i][c0] = lo;
    }
    __syncthreads();
    const float bz = bp[N3 + c0], br = bp[N3 + 128 + c0], bh = bp[N3 + 256 + c0];

    // double-buffered raw gather values (indexed with compile-time t&1 after full unroll)
    unsigned short pq[2][4][3], pl[2][4][3];
#pragma unroll
    for (int i = 0; i < 4; i++) {
        int q = qqA[0][rbase + i], lk = llA[0][rbase + i];
        const unsigned short* qp = g_qgi_h + (size_t)q * N3 + c0;
        const unsigned short* lp = g_lgi_h + (size_t)lk * N3 + c0;
        pq[0][i][0] = qp[0]; pq[0][i][1] = qp[128]; pq[0][i][2] = qp[256];
        pl[0][i][0] = lp[0]; pl[0][i][1] = lp[128]; pl[0][i][2] = lp[256];
    }

#pragma unroll
    for (int t = 0; t < TT; t++) {
        const int cur = t & 1, nxt = cur ^ 1;
        // ---- prefetch t+1 gathers BEFORE this timestep's compute (latency hidden) ----
        if (t + 1 < TT) {
#pragma unroll
            for (int i = 0; i < 4; i++) {
                int q = qqA[t + 1][rbase + i], lk = llA[t + 1][rbase + i];
                const unsigned short* qp = g_qgi_h + (size_t)q * N3 + c0;
                const unsigned short* lp = g_lgi_h + (size_t)lk * N3 + c0;
                pq[nxt][i][0] = qp[0]; pq[nxt][i][1] = qp[128]; pq[nxt][i][2] = qp[256];
                pl[nxt][i][0] = lp[0]; pl[nxt][i][1] = lp[128]; pl[nxt][i][2] = lp[256];
            }
        }
        int msk[4];
#pragma unroll
        for (int i = 0; i < 4; i++) msk[i] = mAsh[t][rbase + i];

        bf16x8 ah[4], al[4];
#pragma unroll
        for (int kc = 0; kc < 4; kc++) {
            ah[kc] = *reinterpret_cast<const bf16x8*>(&hs_hi[cur][l & 15][kc * 32 + (l >> 4) * 8]);
            al[kc] = *reinterpret_cast<const bf16x8*>(&hs_lo[cur][l & 15][kc * 32 + (l >> 4) * 8]);
        }
        f32x4 acc[3];
#pragma unroll
        for (int g = 0; g < 3; g++) acc[g] = (f32x4){0.f, 0.f, 0.f, 0.f};
#pragma unroll
        for (int kc = 0; kc < 4; kc++) {
#pragma unroll
            for (int g = 0; g < 3; g++) {
                bf16x8 bhv = Bh[kc * 3 + g];
                bf16x8 blv = Bl[kc * 3 + g];
                acc[g] = __builtin_amdgcn_mfma_f32_16x16x32_bf16(ah[kc], bhv, acc[g], 0, 0, 0);
                acc[g] = __builtin_amdgcn_mfma_f32_16x16x32_bf16(al[kc], bhv, acc[g], 0, 0, 0);
                acc[g] = __builtin_amdgcn_mfma_f32_16x16x32_bf16(ah[kc], blv, acc[g], 0, 0, 0);
            }
        }
        // epilogue: convert this timestep's (prefetched) gathers, gates, h update
#pragma unroll
        for (int i = 0; i < 4; i++) {
            float gz = h2f(pq[cur][i][0]) + h2f(pl[cur][i][0]);
            float gr = h2f(pq[cur][i][1]) + h2f(pl[cur][i][1]);
            float gh = h2f(pq[cur][i][2]) + h2f(pl[cur][i][2]);
            float zin = acc[0][i] + gz + bz;
            float rin = acc[1][i] + gr + br;
            float zv = fsig(zin);
            float rv = fsig(rin);
            float cand = ftanh(gh + rv * (acc[2][i] + bh));
            float hn = zv * h0[i] + (1.0f - zv) * cand;
            h0[i] = msk[i] ? hn : h0[i];
        }
#pragma unroll
        for (int i = 0; i < 4; i++) {
            unsigned short hi, lo;
            split_bf(h0[i], hi, lo);
            hs_hi[nxt][rbase + i][c0] = hi; hs_lo[nxt][rbase + i][c0] = lo;
        }
        __syncthreads();
    }
#pragma unroll
    for (int i = 0; i < 4; i++)
        g_path[(size_t)(r0 + rbase + i) * DD + c0] = h0[i];
}

// ---------- per-queue segment sum of path states via CSR ----------
__global__ void k_qsum() {
    int w = threadIdx.x >> 6, lane = threadIdx.x & 63;
    int q = blockIdx.x * 4 + w;
    if (q >= NQ) return;
    int s = g_off[q], e = g_off[q + 1];
    float a0 = 0.f, a1 = 0.f;
    for (int i = s; i < e; i++) {
        const float* p = g_path + (size_t)g_col[i] * DD;
        a0 += p[lane]; a1 += p[lane + 64];
    }
    g_psum[(size_t)q * DD + lane] = a0;
    g_psum[(size_t)q * DD + lane + 64] = a1;
}

// ---------- queue GRU via MFMA: K=256 combined [x;h]; nz flags folded in ----------
__global__ __launch_bounds__(256) void k_queue_mfma(const float* __restrict__ bq) {
    __shared__ unsigned short xs_hi[16][136], xs_lo[16][136];
    __shared__ unsigned short hs_hi[16][136], hs_lo[16][136];
    __shared__ int nzf[16];
    const int tid = threadIdx.x, w = tid >> 6, l = tid & 63;
    const int r0 = blockIdx.x * 16;
    if (tid < 16) nzf[tid] = 0;
    for (int idx = tid; idx < 16 * DD; idx += 256) {
        unsigned short hi, lo;
        split_bf(g_psum[(size_t)r0 * DD + idx], hi, lo);
        xs_hi[idx >> 7][idx & 127] = hi; xs_lo[idx >> 7][idx & 127] = lo;
        split_bf(g_queue[(size_t)r0 * DD + idx], hi, lo);
        hs_hi[idx >> 7][idx & 127] = hi; hs_lo[idx >> 7][idx & 127] = lo;
    }
    __syncthreads();
    f32x4 aZ[2], aR[2], aIH[2], aHH[2];
#pragma unroll
    for (int tau = 0; tau < 2; tau++) {
        aZ[tau] = (f32x4){0.f,0.f,0.f,0.f}; aR[tau] = (f32x4){0.f,0.f,0.f,0.f};
        aIH[tau] = (f32x4){0.f,0.f,0.f,0.f}; aHH[tau] = (f32x4){0.f,0.f,0.f,0.f};
    }
#pragma unroll
    for (int kc = 0; kc < 8; kc++) {
        int kk = (kc & 3) * 32 + (l >> 4) * 8;
        bf16x8 ah, al;
        if (kc < 4) {
            ah = *reinterpret_cast<const bf16x8*>(&xs_hi[l & 15][kk]);
            al = *reinterpret_cast<const bf16x8*>(&xs_lo[l & 15][kk]);
        } else {
            ah = *reinterpret_cast<const bf16x8*>(&hs_hi[l & 15][kk]);
            al = *reinterpret_cast<const bf16x8*>(&hs_lo[l & 15][kk]);
        }
#pragma unroll
        for (int g = 0; g < 3; g++) {
#pragma unroll
            for (int tau = 0; tau < 2; tau++) {
                int nt = g * 8 + 2 * w + tau;
                size_t boff = ((size_t)(nt * 8 + kc)) * FR + (size_t)l * 8;
                bf16x8 bhv = *reinterpret_cast<const bf16x8*>(&g_wuq_hi[boff]);
                bf16x8 blv = *reinterpret_cast<const bf16x8*>(&g_wuq_lo[boff]);
                f32x4 a = (g == 0) ? aZ[tau] : (g == 1) ? aR[tau] : (kc < 4 ? aIH[tau] : aHH[tau]);
                a = __builtin_amdgcn_mfma_f32_16x16x32_bf16(ah, bhv, a, 0, 0, 0);
                a = __builtin_amdgcn_mfma_f32_16x16x32_bf16(al, bhv, a, 0, 0, 0);
                a = __builtin_amdgcn_mfma_f32_16x16x32_bf16(ah, blv, a, 0, 0, 0);
                if (g == 0) aZ[tau] = a; else if (g == 1) aR[tau] = a;
                else { if (kc < 4) aIH[tau] = a; else aHH[tau] = a; }
            }
        }
    }
    const int rbase = (l >> 4) * 4;
#pragma unroll
    for (int tau = 0; tau < 2; tau++) {
        int c = 32 * w + (l & 15) + (tau ? 16 : 0);
        float bz0 = bq[c],       bz1 = bq[N3 + c];
        float br0 = bq[128 + c], br1 = bq[N3 + 128 + c];
        float bh0 = bq[256 + c], bh1 = bq[N3 + 256 + c];
#pragma unroll
        for (int i = 0; i < 4; i++) {
            size_t row = (size_t)(r0 + rbase + i);
            float hold = g_queue[row * DD + c];
            float z = fsig(aZ[tau][i] + bz0 + bz1);
            float r = fsig(aR[tau][i] + br0 + br1);
            float cand = ftanh(aIH[tau][i] + bh0 + r * (aHH[tau][i] + bh1));
            float hn = z * hold + (1.0f - z) * cand;
            g_queue[row * DD + c] = hn;
            if (hn != 0.0f) nzf[rbase + i] = 1;
        }
    }
    __syncthreads();
    if (tid < 16) g_nzq[r0 + tid] = nzf[tid];
}

// ---------- link GRU via MFMA: 3 timesteps, fp16 gather, nz flags folded ----------
__global__ __launch_bounds__(256) void k_link_mfma(const float* __restrict__ bl) {
    __shared__ unsigned short hs_hi[16][136], hs_lo[16][136];
    __shared__ int mA[3][16], nzf[16];
    const int tid = threadIdx.x, w = tid >> 6, l = tid & 63;
    const int r0 = blockIdx.x * 16;
    if (tid < 16) nzf[tid] = 0;
    if (tid < 48) {
        int r = tid / 3, j = tid % 3;
        mA[j][r] = g_nzq[3 * (r0 + r) + j];
    }
    const int c0 = 32 * w + (l & 15), c1 = c0 + 16;
    const int rbase = (l >> 4) * 4;
    float h0[4], h1[4];
#pragma unroll
    for (int i = 0; i < 4; i++) {
        h0[i] = g_link[(size_t)(r0 + rbase + i) * DD + c0];
        h1[i] = g_link[(size_t)(r0 + rbase + i) * DD + c1];
    }
#pragma unroll
    for (int i = 0; i < 4; i++) {
        unsigned short hi, lo;
        split_bf(h0[i], hi, lo); hs_hi[rbase + i][c0] = hi; hs_lo[rbase + i][c0] = lo;
        split_bf(h1[i], hi, lo); hs_hi[rbase + i][c1] = hi; hs_lo[rbase + i][c1] = lo;
    }
    __syncthreads();
    float bz[2], br[2], bh[2];
    bz[0] = bl[N3 + c0]; bz[1] = bl[N3 + c1];
    br[0] = bl[N3 + 128 + c0]; br[1] = bl[N3 + 128 + c1];
    bh[0] = bl[N3 + 256 + c0]; bh[1] = bl[N3 + 256 + c1];

    for (int t = 0; t < 3; t++) {
        int msk[4];
#pragma unroll
        for (int i = 0; i < 4; i++) msk[i] = mA[t][rbase + i];
        float gq[2][4][3];
#pragma unroll
        for (int tau = 0; tau < 2; tau++) {
            int cc = tau ? c1 : c0;
#pragma unroll
            for (int i = 0; i < 4; i++) {
                int q = 3 * (r0 + rbase + i) + t;   // queue_to_link = arange: link L owns queues 3L..3L+2
                const unsigned short* qp = g_qgi_h + (size_t)q * N3 + cc;
                gq[tau][i][0] = h2f(qp[0]); gq[tau][i][1] = h2f(qp[128]); gq[tau][i][2] = h2f(qp[256]);
            }
        }
        bf16x8 ah[4], al[4];
#pragma unroll
        for (int kc = 0; kc < 4; kc++) {
            ah[kc] = *reinterpret_cast<const bf16x8*>(&hs_hi[l & 15][kc * 32 + (l >> 4) * 8]);
            al[kc] = *reinterpret_cast<const bf16x8*>(&hs_lo[l & 15][kc * 32 + (l >> 4) * 8]);
        }
        f32x4 acc[3][2];
#pragma unroll
        for (int g = 0; g < 3; g++)
#pragma unroll
            for (int tau = 0; tau < 2; tau++) acc[g][tau] = (f32x4){0.f, 0.f, 0.f, 0.f};
#pragma unroll
        for (int kc = 0; kc < 4; kc++) {
#pragma unroll
            for (int g = 0; g < 3; g++) {
#pragma unroll
                for (int tau = 0; tau < 2; tau++) {
                    int nt = g * 8 + 2 * w + tau;
                    size_t boff = ((size_t)(nt * 4 + kc)) * FR + (size_t)l * 8;
                    bf16x8 bhv = *reinterpret_cast<const bf16x8*>(&g_ulb_hi[boff]);
                    bf16x8 blv = *reinterpret_cast<const bf16x8*>(&g_ulb_lo[boff]);
                    acc[g][tau] = __builtin_amdgcn_mfma_f32_16x16x32_bf16(ah[kc], bhv, acc[g][tau], 0, 0, 0);
                    acc[g][tau] = __builtin_amdgcn_mfma_f32_16x16x32_bf16(al[kc], bhv, acc[g][tau], 0, 0, 0);
                    acc[g][tau] = __builtin_amdgcn_mfma_f32_16x16x32_bf16(ah[kc], blv, acc[g][tau], 0, 0, 0);
                }
            }
        }
        __syncthreads();
#pragma unroll
        for (int tau = 0; tau < 2; tau++) {
#pragma unroll
            for (int i = 0; i < 4; i++) {
                float zin = acc[0][tau][i] + gq[tau][i][0] + bz[tau];
                float rin = acc[1][tau][i] + gq[tau][i][1] + br[tau];
                float hold = tau ? h1[i] : h0[i];
                float zv = fsig(zin);
                float rv = fsig(rin);
                float cand = ftanh(gq[tau][i][2] + rv * (acc[2][tau][i] + bh[tau]));
                float hn = zv * hold + (1.0f - zv) * cand;
                float hout = msk[i] ? hn : hold;
                if (tau) h1[i] = hout; else h0[i] = hout;
            }
        }
#pragma unroll
        for (int i = 0; i < 4; i++) {
            unsigned short hi, lo;
            split_bf(h0[i], hi, lo); hs_hi[rbase + i][c0] = hi; hs_lo[rbase + i][c0] = lo;
            split_bf(h1[i], hi, lo); hs_hi[rbase + i][c1] = hi; hs_lo[rbase + i][c1] = lo;
        }
        __syncthreads();
    }
#pragma unroll
    for (int i = 0; i < 4; i++) {
        g_link[(size_t)(r0 + rbase + i) * DD + c0] = h0[i];
        g_link[(size_t)(r0 + rbase + i) * DD + c1] = h1[i];
        if (h0[i] != 0.0f || h1[i] != 0.0f) nzf[rbase + i] = 1;
    }
    __syncthreads();
    if (tid < 16) g_nzl[r0 + tid] = nzf[tid];
}

// ---------- readout via MFMA ----------
__global__ __launch_bounds__(256) void k_readout_mfma(const float* __restrict__ b1,
                                                      const float* __restrict__ b2,
                                                      const float* __restrict__ W3,
                                                      const float* __restrict__ b3,
                                                      float* __restrict__ out) {
    __shared__ unsigned short s1_hi[16][136], s1_lo[16][136];
    __shared__ unsigned short r1_hi[16][264], r1_lo[16][264];
    __shared__ float r2f[16][256];
    const int tid = threadIdx.x, w = tid >> 6, l = tid & 63;
    const int r0 = blockIdx.x * 16;
    for (int idx = tid; idx < 16 * DD; idx += 256) {
        unsigned short hi, lo;
        split_bf(g_path[(size_t)r0 * DD + idx], hi, lo);
        s1_hi[idx >> 7][idx & 127] = hi; s1_lo[idx >> 7][idx & 127] = lo;
    }
    __syncthreads();
    const int rbase = (l >> 4) * 4;
    {
        f32x4 acc[4];
#pragma unroll
        for (int n = 0; n < 4; n++) acc[n] = (f32x4){0.f, 0.f, 0.f, 0.f};
#pragma unroll
        for (int kc = 0; kc < 4; kc++) {
            int kk = kc * 32 + (l >> 4) * 8;
            bf16x8 ah = *reinterpret_cast<const bf16x8*>(&s1_hi[l & 15][kk]);
            bf16x8 al = *reinterpret_cast<const bf16x8*>(&s1_lo[l & 15][kk]);
#pragma unroll
            for (int n = 0; n < 4; n++) {
                int nt = 4 * w + n;
                size_t boff = ((size_t)(nt * 4 + kc)) * FR + (size_t)l * 8;
                bf16x8 bhv = *reinterpret_cast<const bf16x8*>(&g_w1b_hi[boff]);
                bf16x8 blv = *reinterpret_cast<const bf16x8*>(&g_w1b_lo[boff]);
                acc[n] = __builtin_amdgcn_mfma_f32_16x16x32_bf16(ah, bhv, acc[n], 0, 0, 0);
                acc[n] = __builtin_amdgcn_mfma_f32_16x16x32_bf16(al, bhv, acc[n], 0, 0, 0);
                acc[n] = __builtin_amdgcn_mfma_f32_16x16x32_bf16(ah, blv, acc[n], 0, 0, 0);
            }
        }
#pragma unroll
        for (int n = 0; n < 4; n++) {
            int col = (4 * w + n) * 16 + (l & 15);
#pragma unroll
            for (int i = 0; i < 4; i++) {
                float v = fmaxf(acc[n][i] + b1[col], 0.f);
                unsigned short hi, lo;
                split_bf(v, hi, lo);
                r1_hi[rbase + i][col] = hi; r1_lo[rbase + i][col] = lo;
            }
        }
    }
    __syncthreads();
    {
        f32x4 acc[4];
#pragma unroll
        for (int n = 0; n < 4; n++) acc[n] = (f32x4){0.f, 0.f, 0.f, 0.f};
#pragma unroll
        for (int kc = 0; kc < 8; kc++) {
            int kk = kc * 32 + (l >> 4) * 8;
            bf16x8 ah = *reinterpret_cast<const bf16x8*>(&r1_hi[l & 15][kk]);
            bf16x8 al = *reinterpret_cast<const bf16x8*>(&r1_lo[l & 15][kk]);
#pragma unroll
            for (int n = 0; n < 4; n++) {
                int nt = 4 * w + n;
                size_t boff = ((size_t)(nt * 8 + kc)) * FR + (size_t)l * 8;
                bf16x8 bhv = *reinterpret_cast<const bf16x8*>(&g_w2b_hi[boff]);
                bf16x8 blv = *reinterpret_cast<const bf16x8*>(&g_w2b_lo[boff]);
                acc[n] = __builtin_amdgcn_mfma_f32_16x16x32_bf16(ah, bhv, acc[n], 0, 0, 0);
                acc[n] = __builtin_amdgcn_mfma_f32_16x16x32_bf16(al, bhv, acc[n], 0, 0, 0);
                acc[n] = __builtin_amdgcn_mfma_f32_16x16x32_bf16(ah, blv, acc[n], 0, 0, 0);
            }
        }
#pragma unroll
        for (int n = 0; n < 4; n++) {
            int col = (4 * w + n) * 16 + (l & 15);
#pragma unroll
            for (int i = 0; i < 4; i++)
                r2f[rbase + i][col] = fmaxf(acc[n][i] + b2[col], 0.f);
        }
    }
    __syncthreads();
    {
        float w3a = W3[l], w3b = W3[l + 64], w3c = W3[l + 128], w3d = W3[l + 192];
#pragma unroll
        for (int rr = 0; rr < 4; rr++) {
            int row = w * 4 + rr;
            float s = r2f[row][l] * w3a + r2f[row][l + 64] * w3b +
                      r2f[row][l + 128] * w3c + r2f[row][l + 192] * w3d;
            for (int off = 32; off > 0; off >>= 1) s += __shfl_down(s, off);
            if (l == 0) out[r0 + row] = s + b3[0];
        }
    }
}

extern "C" void kernel_launch(void* const* d_in, const int* in_sizes, int n_in,
                              void* d_out, int out_size, void* d_ws, size_t ws_size,
                              hipStream_t stream) {
    const float* traffic  = (const float*)d_in[0];
    const float* packets  = (const float*)d_in[1];
    const float* capacity = (const float*)d_in[2];
    const float* weight   = (const float*)d_in[3];
    const int* policy     = (const int*)d_in[4];
    const int* priority   = (const int*)d_in[5];
    const int* path_ids   = (const int*)d_in[6];
    const int* l_q_p      = (const int*)d_in[7];
    const int* l_p_s      = (const int*)d_in[8];
    const int* link_to_path    = (const int*)d_in[9];
    const int* queue_to_path   = (const int*)d_in[10];
    const int* path_to_queue   = (const int*)d_in[11];
    const int* sequence_queues = (const int*)d_in[12];
    const float* Wp  = (const float*)d_in[19];
    const float* Up  = (const float*)d_in[20];
    const float* bp  = (const float*)d_in[21];
    const float* Wl  = (const float*)d_in[22];
    const float* Ul  = (const float*)d_in[23];
    const float* bl  = (const float*)d_in[24];
    const float* Wq  = (const float*)d_in[25];
    const float* Uq  = (const float*)d_in[26];
    const float* bq  = (const float*)d_in[27];
    const float* Wr1 = (const float*)d_in[28];
    const float* br1 = (const float*)d_in[29];
    const float* Wr2 = (const float*)d_in[30];
    const float* br2 = (const float*)d_in[31];
    const float* Wr3 = (const float*)d_in[32];
    const float* br3 = (const float*)d_in[33];
    float* out = (float*)d_out;

    k_init_maps<<<(NE + 255) / 256, 256, 0, stream>>>();
    k_fill_maps<<<(NE + 255) / 256, 256, 0, stream>>>(path_ids, l_q_p, l_p_s, queue_to_path,
                                                      link_to_path, sequence_queues);
    k_scan<<<1, 1024, 0, stream>>>();
    k_fill_csr<<<(NE + 255) / 256, 256, 0, stream>>>(sequence_queues, path_to_queue);
    k_init_states<<<(NP * DD + 255) / 256, 256, 0, stream>>>(traffic, packets, capacity,
                                                             policy, weight, priority);
    k_pack<<<192, 256, 0, stream>>>(0, Up, N3);
    k_pack<<<192, 256, 0, stream>>>(1, Wp, N3);
    k_pack<<<192, 256, 0, stream>>>(2, Wp + 128 * N3, N3);
    k_pack<<<192, 256, 0, stream>>>(3, Wl, N3);
    k_pack<<<192, 256, 0, stream>>>(4, Wq, N3);
    k_pack<<<192, 256, 0, stream>>>(5, Uq, N3);
    k_pack<<<192, 256, 0, stream>>>(6, Ul, N3);
    k_pack<<<128, 256, 0, stream>>>(7, Wr1, 256);
    k_pack<<<256, 256, 0, stream>>>(8, Wr2, 256);
    k_nz<<<NQ / 4, 256, 0, stream>>>(0);
    k_nz<<<NL / 4, 256, 0, stream>>>(1);

    for (int it = 0; it < TT; ++it) {
        // path phase: merged projections then fused recurrent MFMA steps (8-wave blocks)
        k_gemm_mfma<<<NQ / 16 + NL / 16, 256, 0, stream>>>(3, bp);
        k_path<<<NP / 16, 512, 0, stream>>>(bp);
        // queue phase (separate qsum for max TLP; nzq folded into k_queue_mfma)
        k_qsum<<<NQ / 4, 256, 0, stream>>>();
        k_queue_mfma<<<NQ / 16, 256, 0, stream>>>(bq);
        // link phase (projection as separate wide GEMM; nzl folded into k_link_mfma)
        k_gemm_mfma<<<NQ / 16, 256, 0, stream>>>(2, bl);
        k_link_mfma<<<NL / 16, 256, 0, stream>>>(bl);
    }

    k_readout_mfma<<<NP / 16, 256, 0, stream>>>(br1, br2, Wr3, br3, out);
}

// Round 14
// 1556.973 us; speedup vs baseline: 1.4413x; 1.0258x over previous
//
#include <hip/hip_runtime.h>
#include <hip/hip_bf16.h>
#include <hip/hip_fp16.h>
#include <math.h>

#define NP 20000
#define NL 4000
#define NQ 12000
#define NE 160000
#define DD 128
#define N3 384
#define TT 8
#define FR 512   // 64 lanes * 8 elems per fragment slot

typedef __attribute__((ext_vector_type(8))) short bf16x8;
typedef __attribute__((ext_vector_type(4))) float f32x4;

// ---------- device global scratch ----------
__device__ float g_path [NP * DD];
__device__ float g_link [NL * DD];
__device__ float g_queue[NQ * DD];
__device__ unsigned short g_qgi_h [NQ * N3];  // fp16: queue @ Wp.q + bp0  (path phase)
__device__ unsigned short g_qgi2_h[NQ * N3];  // fp16: queue @ Wl  + bl0  (link phase)
__device__ unsigned short g_lgi_h [NL * N3];  // fp16: link  @ Wp.l        (path phase)
__device__ float g_psum [NQ * DD];
__device__ int   g_peq  [NE];
__device__ int   g_pel  [NE];
__device__ int   g_counts[NQ];
__device__ int   g_off  [NQ + 1];
__device__ int   g_cur  [NQ];
__device__ int   g_col  [NE];
__device__ int   g_nzq  [NQ];
__device__ int   g_nzl  [NL];
// weight packs, MFMA B-fragment layout: [nt][kc_total][lane=64][j=8], hi/lo split bf16
__device__ unsigned short g_upb_hi[24*4*FR], g_upb_lo[24*4*FR];        // Up
__device__ unsigned short g_wpb_hi[2*24*4*FR], g_wpb_lo[2*24*4*FR];    // Wp (2 halves)
__device__ unsigned short g_wlb_hi[24*4*FR], g_wlb_lo[24*4*FR];        // Wl
__device__ unsigned short g_wuq_hi[24*8*FR], g_wuq_lo[24*8*FR];        // [Wq;Uq] K=256
__device__ unsigned short g_ulb_hi[24*4*FR], g_ulb_lo[24*4*FR];        // Ul
__device__ unsigned short g_w1b_hi[16*4*FR], g_w1b_lo[16*4*FR];        // Wr1
__device__ unsigned short g_w2b_hi[16*8*FR], g_w2b_lo[16*8*FR];        // Wr2

__device__ __forceinline__ float fsig(float x)  { return 1.0f / (1.0f + __expf(-x)); }
__device__ __forceinline__ float ftanh(float x) { return 2.0f / (1.0f + __expf(-2.0f * x)) - 1.0f; }

__device__ __forceinline__ void split_bf(float v, unsigned short& hi, unsigned short& lo) {
    unsigned u = __float_as_uint(v);
    hi = (unsigned short)(u >> 16);
    float lof = v - __uint_as_float(u & 0xFFFF0000u);
    lo = (unsigned short)(__float_as_uint(lof) >> 16);
}
__device__ __forceinline__ unsigned short f2h(float v) {
    __half h = __float2half_rn(v);
    return *reinterpret_cast<unsigned short*>(&h);
}
__device__ __forceinline__ float h2f(unsigned short u) {
    __half h = *reinterpret_cast<__half*>(&u);
    return __half2float(h);
}

// ---------- setup kernels ----------
__global__ void k_init_maps() {
    int i = blockIdx.x * 256 + threadIdx.x;
    if (i < NE) { g_peq[i] = -1; g_pel[i] = -1; }
    if (i < NQ) { g_counts[i] = 0; }
}

__global__ void k_fill_maps(const int* __restrict__ path_ids, const int* __restrict__ l_q_p,
                            const int* __restrict__ l_p_s, const int* __restrict__ queue_to_path,
                            const int* __restrict__ link_to_path, const int* __restrict__ sequence_queues) {
    int i = blockIdx.x * 256 + threadIdx.x;
    if (i < NE) {
        int p = path_ids[i];
        g_peq[p * 8 + l_q_p[i]] = queue_to_path[i];
        g_pel[p * 8 + l_p_s[i]] = link_to_path[i];
        atomicAdd(&g_counts[sequence_queues[i]], 1);
    }
}

__global__ __launch_bounds__(1024) void k_scan() {
    __shared__ int part[1024];
    int tid = threadIdx.x;
    int base = tid * 12;
    int local[12];
    int s = 0;
#pragma unroll
    for (int j = 0; j < 12; j++) {
        int idx = base + j;
        int v = (idx < NQ) ? g_counts[idx] : 0;
        local[j] = s; s += v;
    }
    part[tid] = s;
    __syncthreads();
    for (int off = 1; off < 1024; off <<= 1) {
        int v = (tid >= off) ? part[tid - off] : 0;
        __syncthreads();
        part[tid] += v;
        __syncthreads();
    }
    int pre = (tid > 0) ? part[tid - 1] : 0;
#pragma unroll
    for (int j = 0; j < 12; j++) {
        int idx = base + j;
        if (idx < NQ) { g_off[idx] = pre + local[j]; g_cur[idx] = pre + local[j]; }
    }
    if (tid == 1023) g_off[NQ] = part[1023];
}

__global__ void k_fill_csr(const int* __restrict__ sequence_queues, const int* __restrict__ path_to_queue) {
    int i = blockIdx.x * 256 + threadIdx.x;
    if (i < NE) {
        int q = sequence_queues[i];
        int pos = atomicAdd(&g_cur[q], 1);
        g_col[pos] = path_to_queue[i];
    }
}

__global__ void k_init_states(const float* __restrict__ traffic, const float* __restrict__ packets,
                              const float* __restrict__ capacity, const int* __restrict__ policy,
                              const float* __restrict__ weight, const int* __restrict__ priority) {
    int idx = blockIdx.x * 256 + threadIdx.x;
    if (idx < NP * DD) {
        int p = idx >> 7, d = idx & 127;
        g_path[idx] = (d == 0) ? traffic[p] : (d == 1) ? packets[p] : 0.0f;
    }
    if (idx < NL * DD) {
        int l = idx >> 7, d = idx & 127;
        float v = 0.0f;
        if (d == 0) v = capacity[l];
        else if (d >= 1 && d <= 3) v = (policy[l] == d - 1) ? 1.0f : 0.0f;
        g_link[idx] = v;
    }
    if (idx < NQ * DD) {
        int q = idx >> 7, d = idx & 127;
        float v = 0.0f;
        if (d < 3) v = (priority[q] == d) ? 1.0f : 0.0f;
        else if (d == 3) v = weight[q];
        g_queue[idx] = v;
    }
}

// generic weight pack: W[k][col] -> fragment layout, split bf16 hi/lo
// modes: 0=Up 1=Wp.q 2=Wp.l 3=Wl 4=Wq(kcb0) 5=Uq(kcb4) 6=Ul 7=Wr1 8=Wr2
__global__ void k_pack(int mode, const float* __restrict__ W, int ldn) {
    unsigned short *dhi, *dlo;
    int nt_cnt, kc_cnt, kc_total, kc_base;
    if (mode == 0)      { dhi=g_upb_hi; dlo=g_upb_lo; nt_cnt=24; kc_cnt=4; kc_total=4; kc_base=0; }
    else if (mode == 1) { dhi=g_wpb_hi; dlo=g_wpb_lo; nt_cnt=24; kc_cnt=4; kc_total=4; kc_base=0; }
    else if (mode == 2) { dhi=g_wpb_hi+24*4*FR; dlo=g_wpb_lo+24*4*FR; nt_cnt=24; kc_cnt=4; kc_total=4; kc_base=0; }
    else if (mode == 3) { dhi=g_wlb_hi; dlo=g_wlb_lo; nt_cnt=24; kc_cnt=4; kc_total=4; kc_base=0; }
    else if (mode == 4) { dhi=g_wuq_hi; dlo=g_wuq_lo; nt_cnt=24; kc_cnt=4; kc_total=8; kc_base=0; }
    else if (mode == 5) { dhi=g_wuq_hi; dlo=g_wuq_lo; nt_cnt=24; kc_cnt=4; kc_total=8; kc_base=4; }
    else if (mode == 6) { dhi=g_ulb_hi; dlo=g_ulb_lo; nt_cnt=24; kc_cnt=4; kc_total=4; kc_base=0; }
    else if (mode == 7) { dhi=g_w1b_hi; dlo=g_w1b_lo; nt_cnt=16; kc_cnt=4; kc_total=4; kc_base=0; }
    else                { dhi=g_w2b_hi; dlo=g_w2b_lo; nt_cnt=16; kc_cnt=8; kc_total=8; kc_base=0; }
    int tot = nt_cnt * kc_cnt * FR;
    int idx = blockIdx.x * 256 + threadIdx.x;
    if (idx >= tot) return;
    int j = idx & 7, lane = (idx >> 3) & 63;
    int kc = (idx >> 9) % kc_cnt, nt = idx / (kc_cnt * FR);
    int k = kc * 32 + (lane >> 4) * 8 + j;
    int col = nt * 16 + (lane & 15);
    float v = W[(size_t)k * ldn + col];
    unsigned short hi, lo;
    split_bf(v, hi, lo);
    size_t o = ((size_t)(nt * kc_total + kc_base + kc)) * FR + (size_t)lane * 8 + j;
    dhi[o] = hi; dlo[o] = lo;
}

// initial nonzero flags
__global__ void k_nz(int mode) {
    const float* st = mode ? g_link : g_queue;
    int n = mode ? NL : NQ;
    int* outf = mode ? g_nzl : g_nzq;
    int w = threadIdx.x >> 6, lane = threadIdx.x & 63;
    int row = blockIdx.x * 4 + w;
    if (row < n) {
        const float* r = st + (size_t)row * DD;
        bool nz = (r[lane] != 0.0f) || (r[lane + 64] != 0.0f);
        unsigned long long b = __ballot(nz);
        if (lane == 0) outf[row] = (b != 0ULL) ? 1 : 0;
    }
}

// ---------- setup-only projection GEMM (initial states) ----------
// blocks [0, NQ/16): g_queue@Wp.q + bp0 -> g_qgi_h ; [NQ/16, +NL/16): g_link@Wp.l -> g_lgi_h
__global__ __launch_bounds__(256) void k_gemm_mfma(const float* __restrict__ bias) {
    const float* A; unsigned short* C; const unsigned short *Bh, *Bl;
    int r0; bool useB;
    if (blockIdx.x < NQ / 16) {
        A = g_queue; C = g_qgi_h; Bh = g_wpb_hi; Bl = g_wpb_lo;
        r0 = blockIdx.x * 16; useB = true;
    } else {
        A = g_link; C = g_lgi_h; Bh = g_wpb_hi + 24*4*FR; Bl = g_wpb_lo + 24*4*FR;
        r0 = (blockIdx.x - NQ / 16) * 16; useB = false;
    }
    __shared__ unsigned short as_hi[16][136], as_lo[16][136];
    const int tid = threadIdx.x, w = tid >> 6, l = tid & 63;
    for (int idx = tid; idx < 16 * DD; idx += 256) {
        unsigned short hi, lo;
        split_bf(A[(size_t)r0 * DD + idx], hi, lo);
        as_hi[idx >> 7][idx & 127] = hi; as_lo[idx >> 7][idx & 127] = lo;
    }
    __syncthreads();
    f32x4 acc[6];
#pragma unroll
    for (int n = 0; n < 6; n++) acc[n] = (f32x4){0.f, 0.f, 0.f, 0.f};
#pragma unroll
    for (int kc = 0; kc < 4; kc++) {
        int kk = kc * 32 + (l >> 4) * 8;
        bf16x8 ah = *reinterpret_cast<const bf16x8*>(&as_hi[l & 15][kk]);
        bf16x8 al = *reinterpret_cast<const bf16x8*>(&as_lo[l & 15][kk]);
#pragma unroll
        for (int n = 0; n < 6; n++) {
            int nt = 6 * w + n;
            size_t boff = ((size_t)(nt * 4 + kc)) * FR + (size_t)l * 8;
            bf16x8 bhv = *reinterpret_cast<const bf16x8*>(&Bh[boff]);
            bf16x8 blv = *reinterpret_cast<const bf16x8*>(&Bl[boff]);
            acc[n] = __builtin_amdgcn_mfma_f32_16x16x32_bf16(ah, bhv, acc[n], 0, 0, 0);
            acc[n] = __builtin_amdgcn_mfma_f32_16x16x32_bf16(al, bhv, acc[n], 0, 0, 0);
            acc[n] = __builtin_amdgcn_mfma_f32_16x16x32_bf16(ah, blv, acc[n], 0, 0, 0);
        }
    }
    const int rbase = (l >> 4) * 4;
#pragma unroll
    for (int n = 0; n < 6; n++) {
        int col = (6 * w + n) * 16 + (l & 15);
        float bv = useB ? bias[col] : 0.f;
#pragma unroll
        for (int i = 0; i < 4; i++)
            C[(size_t)(r0 + rbase + i) * N3 + col] = f2h(acc[n][i] + bv);
    }
}

// ---------- fused path GRU: 8 waves, one 16-col tile each, B in regs, gather prefetch ----------
__global__ __launch_bounds__(512, 2) void k_path(const float* __restrict__ bp) {
    __shared__ unsigned short hs_hi[2][16][136];
    __shared__ unsigned short hs_lo[2][16][136];
    __shared__ int qqA[8][16], llA[8][16], mAsh[8][16];
    const int tid = threadIdx.x;
    const int w = tid >> 6, l = tid & 63;
    const int r0 = blockIdx.x * 16;
    if (tid < 128) {
        int r = tid >> 3, t = tid & 7;
        int e = (r0 + r) * 8 + t;
        int qq = g_peq[e], ll = g_pel[e];
        qqA[t][r] = qq; llA[t][r] = ll;
        mAsh[t][r] = (g_nzq[qq] | g_nzl[ll]);
    }
    const int c0 = 16 * w + (l & 15);           // each wave owns one 16-col tile
    const int rbase = (l >> 4) * 4;
    // ---- hoist loop-invariant B fragments into registers (12 pairs = 96 VGPRs) ----
    bf16x8 Bh[12], Bl[12];
#pragma unroll
    for (int kc = 0; kc < 4; kc++) {
#pragma unroll
        for (int g = 0; g < 3; g++) {
            int nt = g * 8 + w;
            size_t boff = ((size_t)(nt * 4 + kc) * 64 + l) * 8;
            Bh[kc * 3 + g] = *reinterpret_cast<const bf16x8*>(&g_upb_hi[boff]);
            Bl[kc * 3 + g] = *reinterpret_cast<const bf16x8*>(&g_upb_lo[boff]);
        }
    }
    float h0[4];
#pragma unroll
    for (int i = 0; i < 4; i++)
        h0[i] = g_path[(size_t)(r0 + rbase + i) * DD + c0];
#pragma unroll
    for (int i = 0; i < 4; i++) {
        unsigned short hi, lo;
        split_bf(h0[i], hi, lo);
        hs_hi[0][rbase + i][c0] = hi; hs_lo[0][rbase + i][c0] = lo;
    }
    __syncthreads();
    const float bz = bp[N3 + c0], br = bp[N3 + 128 + c0], bh = bp[N3 + 256 + c0];

    // double-buffered raw gather values (indexed with compile-time t&1 after full unroll)
    unsigned short pq[2][4][3], pl[2][4][3];
#pragma unroll
    for (int i = 0; i < 4; i++) {
        int q = qqA[0][rbase + i], lk = llA[0][rbase + i];
        const unsigned short* qp = g_qgi_h + (size_t)q * N3 + c0;
        const unsigned short* lp = g_lgi_h + (size_t)lk * N3 + c0;
        pq[0][i][0] = qp[0]; pq[0][i][1] = qp[128]; pq[0][i][2] = qp[256];
        pl[0][i][0] = lp[0]; pl[0][i][1] = lp[128]; pl[0][i][2] = lp[256];
    }

#pragma unroll
    for (int t = 0; t < TT; t++) {
        const int cur = t & 1, nxt = cur ^ 1;
        // ---- prefetch t+1 gathers BEFORE this timestep's compute (latency hidden) ----
        if (t + 1 < TT) {
#pragma unroll
            for (int i = 0; i < 4; i++) {
                int q = qqA[t + 1][rbase + i], lk = llA[t + 1][rbase + i];
                const unsigned short* qp = g_qgi_h + (size_t)q * N3 + c0;
                const unsigned short* lp = g_lgi_h + (size_t)lk * N3 + c0;
                pq[nxt][i][0] = qp[0]; pq[nxt][i][1] = qp[128]; pq[nxt][i][2] = qp[256];
                pl[nxt][i][0] = lp[0]; pl[nxt][i][1] = lp[128]; pl[nxt][i][2] = lp[256];
            }
        }
        int msk[4];
#pragma unroll
        for (int i = 0; i < 4; i++) msk[i] = mAsh[t][rbase + i];

        bf16x8 ah[4], al[4];
#pragma unroll
        for (int kc = 0; kc < 4; kc++) {
            ah[kc] = *reinterpret_cast<const bf16x8*>(&hs_hi[cur][l & 15][kc * 32 + (l >> 4) * 8]);
            al[kc] = *reinterpret_cast<const bf16x8*>(&hs_lo[cur][l & 15][kc * 32 + (l >> 4) * 8]);
        }
        f32x4 acc[3];
#pragma unroll
        for (int g = 0; g < 3; g++) acc[g] = (f32x4){0.f, 0.f, 0.f, 0.f};
#pragma unroll
        for (int kc = 0; kc < 4; kc++) {
#pragma unroll
            for (int g = 0; g < 3; g++) {
                bf16x8 bhv = Bh[kc * 3 + g];
                bf16x8 blv = Bl[kc * 3 + g];
                acc[g] = __builtin_amdgcn_mfma_f32_16x16x32_bf16(ah[kc], bhv, acc[g], 0, 0, 0);
                acc[g] = __builtin_amdgcn_mfma_f32_16x16x32_bf16(al[kc], bhv, acc[g], 0, 0, 0);
                acc[g] = __builtin_amdgcn_mfma_f32_16x16x32_bf16(ah[kc], blv, acc[g], 0, 0, 0);
            }
        }
        // epilogue: convert this timestep's (prefetched) gathers, gates, h update
#pragma unroll
        for (int i = 0; i < 4; i++) {
            float gz = h2f(pq[cur][i][0]) + h2f(pl[cur][i][0]);
            float gr = h2f(pq[cur][i][1]) + h2f(pl[cur][i][1]);
            float gh = h2f(pq[cur][i][2]) + h2f(pl[cur][i][2]);
            float zin = acc[0][i] + gz + bz;
            float rin = acc[1][i] + gr + br;
            float zv = fsig(zin);
            float rv = fsig(rin);
            float cand = ftanh(gh + rv * (acc[2][i] + bh));
            float hn = zv * h0[i] + (1.0f - zv) * cand;
            h0[i] = msk[i] ? hn : h0[i];
        }
#pragma unroll
        for (int i = 0; i < 4; i++) {
            unsigned short hi, lo;
            split_bf(h0[i], hi, lo);
            hs_hi[nxt][rbase + i][c0] = hi; hs_lo[nxt][rbase + i][c0] = lo;
        }
        __syncthreads();
    }
#pragma unroll
    for (int i = 0; i < 4; i++)
        g_path[(size_t)(r0 + rbase + i) * DD + c0] = h0[i];
}

// ---------- per-queue segment sum of path states via CSR ----------
__global__ void k_qsum() {
    int w = threadIdx.x >> 6, lane = threadIdx.x & 63;
    int q = blockIdx.x * 4 + w;
    if (q >= NQ) return;
    int s = g_off[q], e = g_off[q + 1];
    float a0 = 0.f, a1 = 0.f;
    for (int i = s; i < e; i++) {
        const float* p = g_path + (size_t)g_col[i] * DD;
        a0 += p[lane]; a1 += p[lane + 64];
    }
    g_psum[(size_t)q * DD + lane] = a0;
    g_psum[(size_t)q * DD + lane + 64] = a1;
}

// ---------- queue GRU via MFMA + fused projections of the NEW state ----------
// after computing hn: hn@Wl+bl0 -> g_qgi2_h (link phase, this iter)
//                     hn@Wp.q+bp0 -> g_qgi_h (path phase, next iter)
__global__ __launch_bounds__(256) void k_queue_mfma(const float* __restrict__ bq,
                                                    const float* __restrict__ bl,
                                                    const float* __restrict__ bp) {
    __shared__ unsigned short xs_hi[16][136], xs_lo[16][136];
    __shared__ unsigned short hs_hi[16][136], hs_lo[16][136];
    __shared__ int nzf[16];
    const int tid = threadIdx.x, w = tid >> 6, l = tid & 63;
    const int r0 = blockIdx.x * 16;
    if (tid < 16) nzf[tid] = 0;
    for (int idx = tid; idx < 16 * DD; idx += 256) {
        unsigned short hi, lo;
        split_bf(g_psum[(size_t)r0 * DD + idx], hi, lo);
        xs_hi[idx >> 7][idx & 127] = hi; xs_lo[idx >> 7][idx & 127] = lo;
        split_bf(g_queue[(size_t)r0 * DD + idx], hi, lo);
        hs_hi[idx >> 7][idx & 127] = hi; hs_lo[idx >> 7][idx & 127] = lo;
    }
    __syncthreads();
    f32x4 aZ[2], aR[2], aIH[2], aHH[2];
#pragma unroll
    for (int tau = 0; tau < 2; tau++) {
        aZ[tau] = (f32x4){0.f,0.f,0.f,0.f}; aR[tau] = (f32x4){0.f,0.f,0.f,0.f};
        aIH[tau] = (f32x4){0.f,0.f,0.f,0.f}; aHH[tau] = (f32x4){0.f,0.f,0.f,0.f};
    }
#pragma unroll
    for (int kc = 0; kc < 8; kc++) {
        int kk = (kc & 3) * 32 + (l >> 4) * 8;
        bf16x8 ah, al;
        if (kc < 4) {
            ah = *reinterpret_cast<const bf16x8*>(&xs_hi[l & 15][kk]);
            al = *reinterpret_cast<const bf16x8*>(&xs_lo[l & 15][kk]);
        } else {
            ah = *reinterpret_cast<const bf16x8*>(&hs_hi[l & 15][kk]);
            al = *reinterpret_cast<const bf16x8*>(&hs_lo[l & 15][kk]);
        }
#pragma unroll
        for (int g = 0; g < 3; g++) {
#pragma unroll
            for (int tau = 0; tau < 2; tau++) {
                int nt = g * 8 + 2 * w + tau;
                size_t boff = ((size_t)(nt * 8 + kc)) * FR + (size_t)l * 8;
                bf16x8 bhv = *reinterpret_cast<const bf16x8*>(&g_wuq_hi[boff]);
                bf16x8 blv = *reinterpret_cast<const bf16x8*>(&g_wuq_lo[boff]);
                f32x4 a = (g == 0) ? aZ[tau] : (g == 1) ? aR[tau] : (kc < 4 ? aIH[tau] : aHH[tau]);
                a = __builtin_amdgcn_mfma_f32_16x16x32_bf16(ah, bhv, a, 0, 0, 0);
                a = __builtin_amdgcn_mfma_f32_16x16x32_bf16(al, bhv, a, 0, 0, 0);
                a = __builtin_amdgcn_mfma_f32_16x16x32_bf16(ah, blv, a, 0, 0, 0);
                if (g == 0) aZ[tau] = a; else if (g == 1) aR[tau] = a;
                else { if (kc < 4) aIH[tau] = a; else aHH[tau] = a; }
            }
        }
    }
    const int rbase = (l >> 4) * 4;
    float hnv[2][4];
#pragma unroll
    for (int tau = 0; tau < 2; tau++) {
        int c = 32 * w + (l & 15) + (tau ? 16 : 0);
        float bz0 = bq[c],       bz1 = bq[N3 + c];
        float br0 = bq[128 + c], br1 = bq[N3 + 128 + c];
        float bh0 = bq[256 + c], bh1 = bq[N3 + 256 + c];
#pragma unroll
        for (int i = 0; i < 4; i++) {
            size_t row = (size_t)(r0 + rbase + i);
            float hold = g_queue[row * DD + c];
            float z = fsig(aZ[tau][i] + bz0 + bz1);
            float r = fsig(aR[tau][i] + br0 + br1);
            float cand = ftanh(aIH[tau][i] + bh0 + r * (aHH[tau][i] + bh1));
            float hn = z * hold + (1.0f - z) * cand;
            g_queue[row * DD + c] = hn;
            hnv[tau][i] = hn;
            if (hn != 0.0f) nzf[rbase + i] = 1;
        }
    }
    __syncthreads();   // all waves done reading hs (old h) before overwrite
    if (tid < 16) g_nzq[r0 + tid] = nzf[tid];
#pragma unroll
    for (int tau = 0; tau < 2; tau++) {
        int c = 32 * w + (l & 15) + (tau ? 16 : 0);
#pragma unroll
        for (int i = 0; i < 4; i++) {
            unsigned short hi, lo;
            split_bf(hnv[tau][i], hi, lo);
            hs_hi[rbase + i][c] = hi; hs_lo[rbase + i][c] = lo;
        }
    }
    __syncthreads();
    // A fragments of new state
    bf16x8 ah[4], al[4];
#pragma unroll
    for (int kc = 0; kc < 4; kc++) {
        int kk = kc * 32 + (l >> 4) * 8;
        ah[kc] = *reinterpret_cast<const bf16x8*>(&hs_hi[l & 15][kk]);
        al[kc] = *reinterpret_cast<const bf16x8*>(&hs_lo[l & 15][kk]);
    }
    // projection 1: hn @ Wl + bl0 -> g_qgi2_h
    {
        f32x4 acc[6];
#pragma unroll
        for (int n = 0; n < 6; n++) acc[n] = (f32x4){0.f, 0.f, 0.f, 0.f};
#pragma unroll
        for (int kc = 0; kc < 4; kc++) {
#pragma unroll
            for (int n = 0; n < 6; n++) {
                int nt = 6 * w + n;
                size_t boff = ((size_t)(nt * 4 + kc)) * FR + (size_t)l * 8;
                bf16x8 bhv = *reinterpret_cast<const bf16x8*>(&g_wlb_hi[boff]);
                bf16x8 blv = *reinterpret_cast<const bf16x8*>(&g_wlb_lo[boff]);
                acc[n] = __builtin_amdgcn_mfma_f32_16x16x32_bf16(ah[kc], bhv, acc[n], 0, 0, 0);
                acc[n] = __builtin_amdgcn_mfma_f32_16x16x32_bf16(al[kc], bhv, acc[n], 0, 0, 0);
                acc[n] = __builtin_amdgcn_mfma_f32_16x16x32_bf16(ah[kc], blv, acc[n], 0, 0, 0);
            }
        }
#pragma unroll
        for (int n = 0; n < 6; n++) {
            int col = (6 * w + n) * 16 + (l & 15);
            float bv = bl[col];
#pragma unroll
            for (int i = 0; i < 4; i++)
                g_qgi2_h[(size_t)(r0 + rbase + i) * N3 + col] = f2h(acc[n][i] + bv);
        }
    }
    // projection 2: hn @ Wp.q + bp0 -> g_qgi_h
    {
        f32x4 acc[6];
#pragma unroll
        for (int n = 0; n < 6; n++) acc[n] = (f32x4){0.f, 0.f, 0.f, 0.f};
#pragma unroll
        for (int kc = 0; kc < 4; kc++) {
#pragma unroll
            for (int n = 0; n < 6; n++) {
                int nt = 6 * w + n;
                size_t boff = ((size_t)(nt * 4 + kc)) * FR + (size_t)l * 8;
                bf16x8 bhv = *reinterpret_cast<const bf16x8*>(&g_wpb_hi[boff]);
                bf16x8 blv = *reinterpret_cast<const bf16x8*>(&g_wpb_lo[boff]);
                acc[n] = __builtin_amdgcn_mfma_f32_16x16x32_bf16(ah[kc], bhv, acc[n], 0, 0, 0);
                acc[n] = __builtin_amdgcn_mfma_f32_16x16x32_bf16(al[kc], bhv, acc[n], 0, 0, 0);
                acc[n] = __builtin_amdgcn_mfma_f32_16x16x32_bf16(ah[kc], blv, acc[n], 0, 0, 0);
            }
        }
#pragma unroll
        for (int n = 0; n < 6; n++) {
            int col = (6 * w + n) * 16 + (l & 15);
            float bv = bp[col];
#pragma unroll
            for (int i = 0; i < 4; i++)
                g_qgi_h[(size_t)(r0 + rbase + i) * N3 + col] = f2h(acc[n][i] + bv);
        }
    }
}

// ---------- link GRU via MFMA + fused projection of the NEW state ----------
__global__ __launch_bounds__(256) void k_link_mfma(const float* __restrict__ bl) {
    __shared__ unsigned short hs_hi[16][136], hs_lo[16][136];
    __shared__ int mA[3][16], nzf[16];
    const int tid = threadIdx.x, w = tid >> 6, l = tid & 63;
    const int r0 = blockIdx.x * 16;
    if (tid < 16) nzf[tid] = 0;
    if (tid < 48) {
        int r = tid / 3, j = tid % 3;
        mA[j][r] = g_nzq[3 * (r0 + r) + j];
    }
    const int c0 = 32 * w + (l & 15), c1 = c0 + 16;
    const int rbase = (l >> 4) * 4;
    float h0[4], h1[4];
#pragma unroll
    for (int i = 0; i < 4; i++) {
        h0[i] = g_link[(size_t)(r0 + rbase + i) * DD + c0];
        h1[i] = g_link[(size_t)(r0 + rbase + i) * DD + c1];
    }
#pragma unroll
    for (int i = 0; i < 4; i++) {
        unsigned short hi, lo;
        split_bf(h0[i], hi, lo); hs_hi[rbase + i][c0] = hi; hs_lo[rbase + i][c0] = lo;
        split_bf(h1[i], hi, lo); hs_hi[rbase + i][c1] = hi; hs_lo[rbase + i][c1] = lo;
    }
    __syncthreads();
    float bz[2], br[2], bh[2];
    bz[0] = bl[N3 + c0]; bz[1] = bl[N3 + c1];
    br[0] = bl[N3 + 128 + c0]; br[1] = bl[N3 + 128 + c1];
    bh[0] = bl[N3 + 256 + c0]; bh[1] = bl[N3 + 256 + c1];

    for (int t = 0; t < 3; t++) {
        int msk[4];
#pragma unroll
        for (int i = 0; i < 4; i++) msk[i] = mA[t][rbase + i];
        float gq[2][4][3];
#pragma unroll
        for (int tau = 0; tau < 2; tau++) {
            int cc = tau ? c1 : c0;
#pragma unroll
            for (int i = 0; i < 4; i++) {
                int q = 3 * (r0 + rbase + i) + t;   // queue_to_link = arange: link L owns queues 3L..3L+2
                const unsigned short* qp = g_qgi2_h + (size_t)q * N3 + cc;
                gq[tau][i][0] = h2f(qp[0]); gq[tau][i][1] = h2f(qp[128]); gq[tau][i][2] = h2f(qp[256]);
            }
        }
        bf16x8 ah[4], al[4];
#pragma unroll
        for (int kc = 0; kc < 4; kc++) {
            ah[kc] = *reinterpret_cast<const bf16x8*>(&hs_hi[l & 15][kc * 32 + (l >> 4) * 8]);
            al[kc] = *reinterpret_cast<const bf16x8*>(&hs_lo[l & 15][kc * 32 + (l >> 4) * 8]);
        }
        f32x4 acc[3][2];
#pragma unroll
        for (int g = 0; g < 3; g++)
#pragma unroll
            for (int tau = 0; tau < 2; tau++) acc[g][tau] = (f32x4){0.f, 0.f, 0.f, 0.f};
#pragma unroll
        for (int kc = 0; kc < 4; kc++) {
#pragma unroll
            for (int g = 0; g < 3; g++) {
#pragma unroll
                for (int tau = 0; tau < 2; tau++) {
                    int nt = g * 8 + 2 * w + tau;
                    size_t boff = ((size_t)(nt * 4 + kc)) * FR + (size_t)l * 8;
                    bf16x8 bhv = *reinterpret_cast<const bf16x8*>(&g_ulb_hi[boff]);
                    bf16x8 blv = *reinterpret_cast<const bf16x8*>(&g_ulb_lo[boff]);
                    acc[g][tau] = __builtin_amdgcn_mfma_f32_16x16x32_bf16(ah[kc], bhv, acc[g][tau], 0, 0, 0);
                    acc[g][tau] = __builtin_amdgcn_mfma_f32_16x16x32_bf16(al[kc], bhv, acc[g][tau], 0, 0, 0);
                    acc[g][tau] = __builtin_amdgcn_mfma_f32_16x16x32_bf16(ah[kc], blv, acc[g][tau], 0, 0, 0);
                }
            }
        }
        __syncthreads();
#pragma unroll
        for (int tau = 0; tau < 2; tau++) {
#pragma unroll
            for (int i = 0; i < 4; i++) {
                float zin = acc[0][tau][i] + gq[tau][i][0] + bz[tau];
                float rin = acc[1][tau][i] + gq[tau][i][1] + br[tau];
                float hold = tau ? h1[i] : h0[i];
                float zv = fsig(zin);
                float rv = fsig(rin);
                float cand = ftanh(gq[tau][i][2] + rv * (acc[2][tau][i] + bh[tau]));
                float hn = zv * hold + (1.0f - zv) * cand;
                float hout = msk[i] ? hn : hold;
                if (tau) h1[i] = hout; else h0[i] = hout;
            }
        }
#pragma unroll
        for (int i = 0; i < 4; i++) {
            unsigned short hi, lo;
            split_bf(h0[i], hi, lo); hs_hi[rbase + i][c0] = hi; hs_lo[rbase + i][c0] = lo;
            split_bf(h1[i], hi, lo); hs_hi[rbase + i][c1] = hi; hs_lo[rbase + i][c1] = lo;
        }
        __syncthreads();
    }
#pragma unroll
    for (int i = 0; i < 4; i++) {
        g_link[(size_t)(r0 + rbase + i) * DD + c0] = h0[i];
        g_link[(size_t)(r0 + rbase + i) * DD + c1] = h1[i];
        if (h0[i] != 0.0f || h1[i] != 0.0f) nzf[rbase + i] = 1;
    }
    __syncthreads();
    if (tid < 16) g_nzl[r0 + tid] = nzf[tid];
    // fused projection of NEW link state: hl @ Wp.l -> g_lgi_h (no bias)
    {
        bf16x8 ah[4], al[4];
#pragma unroll
        for (int kc = 0; kc < 4; kc++) {
            int kk = kc * 32 + (l >> 4) * 8;
            ah[kc] = *reinterpret_cast<const bf16x8*>(&hs_hi[l & 15][kk]);
            al[kc] = *reinterpret_cast<const bf16x8*>(&hs_lo[l & 15][kk]);
        }
        f32x4 acc[6];
#pragma unroll
        for (int n = 0; n < 6; n++) acc[n] = (f32x4){0.f, 0.f, 0.f, 0.f};
#pragma unroll
        for (int kc = 0; kc < 4; kc++) {
#pragma unroll
            for (int n = 0; n < 6; n++) {
                int nt = 6 * w + n;
                size_t boff = ((size_t)(nt * 4 + kc)) * FR + (size_t)l * 8;
                bf16x8 bhv = *reinterpret_cast<const bf16x8*>(&g_wpb_hi[24*4*FR + boff]);
                bf16x8 blv = *reinterpret_cast<const bf16x8*>(&g_wpb_lo[24*4*FR + boff]);
                acc[n] = __builtin_amdgcn_mfma_f32_16x16x32_bf16(ah[kc], bhv, acc[n], 0, 0, 0);
                acc[n] = __builtin_amdgcn_mfma_f32_16x16x32_bf16(al[kc], bhv, acc[n], 0, 0, 0);
                acc[n] = __builtin_amdgcn_mfma_f32_16x16x32_bf16(ah[kc], blv, acc[n], 0, 0, 0);
            }
        }
#pragma unroll
        for (int n = 0; n < 6; n++) {
            int col = (6 * w + n) * 16 + (l & 15);
#pragma unroll
            for (int i = 0; i < 4; i++)
                g_lgi_h[(size_t)(r0 + rbase + i) * N3 + col] = f2h(acc[n][i]);
        }
    }
}

// ---------- readout via MFMA ----------
__global__ __launch_bounds__(256) void k_readout_mfma(const float* __restrict__ b1,
                                                      const float* __restrict__ b2,
                                                      const float* __restrict__ W3,
                                                      const float* __restrict__ b3,
                                                      float* __restrict__ out) {
    __shared__ unsigned short s1_hi[16][136], s1_lo[16][136];
    __shared__ unsigned short r1_hi[16][264], r1_lo[16][264];
    __shared__ float r2f[16][256];
    const int tid = threadIdx.x, w = tid >> 6, l = tid & 63;
    const int r0 = blockIdx.x * 16;
    for (int idx = tid; idx < 16 * DD; idx += 256) {
        unsigned short hi, lo;
        split_bf(g_path[(size_t)r0 * DD + idx], hi, lo);
        s1_hi[idx >> 7][idx & 127] = hi; s1_lo[idx >> 7][idx & 127] = lo;
    }
    __syncthreads();
    const int rbase = (l >> 4) * 4;
    {
        f32x4 acc[4];
#pragma unroll
        for (int n = 0; n < 4; n++) acc[n] = (f32x4){0.f, 0.f, 0.f, 0.f};
#pragma unroll
        for (int kc = 0; kc < 4; kc++) {
            int kk = kc * 32 + (l >> 4) * 8;
            bf16x8 ah = *reinterpret_cast<const bf16x8*>(&s1_hi[l & 15][kk]);
            bf16x8 al = *reinterpret_cast<const bf16x8*>(&s1_lo[l & 15][kk]);
#pragma unroll
            for (int n = 0; n < 4; n++) {
                int nt = 4 * w + n;
                size_t boff = ((size_t)(nt * 4 + kc)) * FR + (size_t)l * 8;
                bf16x8 bhv = *reinterpret_cast<const bf16x8*>(&g_w1b_hi[boff]);
                bf16x8 blv = *reinterpret_cast<const bf16x8*>(&g_w1b_lo[boff]);
                acc[n] = __builtin_amdgcn_mfma_f32_16x16x32_bf16(ah, bhv, acc[n], 0, 0, 0);
                acc[n] = __builtin_amdgcn_mfma_f32_16x16x32_bf16(al, bhv, acc[n], 0, 0, 0);
                acc[n] = __builtin_amdgcn_mfma_f32_16x16x32_bf16(ah, blv, acc[n], 0, 0, 0);
            }
        }
#pragma unroll
        for (int n = 0; n < 4; n++) {
            int col = (4 * w + n) * 16 + (l & 15);
#pragma unroll
            for (int i = 0; i < 4; i++) {
                float v = fmaxf(acc[n][i] + b1[col], 0.f);
                unsigned short hi, lo;
                split_bf(v, hi, lo);
                r1_hi[rbase + i][col] = hi; r1_lo[rbase + i][col] = lo;
            }
        }
    }
    __syncthreads();
    {
        f32x4 acc[4];
#pragma unroll
        for (int n = 0; n < 4; n++) acc[n] = (f32x4){0.f, 0.f, 0.f, 0.f};
#pragma unroll
        for (int kc = 0; kc < 8; kc++) {
            int kk = kc * 32 + (l >> 4) * 8;
            bf16x8 ah = *reinterpret_cast<const bf16x8*>(&r1_hi[l & 15][kk]);
            bf16x8 al = *reinterpret_cast<const bf16x8*>(&r1_lo[l & 15][kk]);
#pragma unroll
            for (int n = 0; n < 4; n++) {
                int nt = 4 * w + n;
                size_t boff = ((size_t)(nt * 8 + kc)) * FR + (size_t)l * 8;
                bf16x8 bhv = *reinterpret_cast<const bf16x8*>(&g_w2b_hi[boff]);
                bf16x8 blv = *reinterpret_cast<const bf16x8*>(&g_w2b_lo[boff]);
                acc[n] = __builtin_amdgcn_mfma_f32_16x16x32_bf16(ah, bhv, acc[n], 0, 0, 0);
                acc[n] = __builtin_amdgcn_mfma_f32_16x16x32_bf16(al, bhv, acc[n], 0, 0, 0);
                acc[n] = __builtin_amdgcn_mfma_f32_16x16x32_bf16(ah, blv, acc[n], 0, 0, 0);
            }
        }
#pragma unroll
        for (int n = 0; n < 4; n++) {
            int col = (4 * w + n) * 16 + (l & 15);
#pragma unroll
            for (int i = 0; i < 4; i++)
                r2f[rbase + i][col] = fmaxf(acc[n][i] + b2[col], 0.f);
        }
    }
    __syncthreads();
    {
        float w3a = W3[l], w3b = W3[l + 64], w3c = W3[l + 128], w3d = W3[l + 192];
#pragma unroll
        for (int rr = 0; rr < 4; rr++) {
            int row = w * 4 + rr;
            float s = r2f[row][l] * w3a + r2f[row][l + 64] * w3b +
                      r2f[row][l + 128] * w3c + r2f[row][l + 192] * w3d;
            for (int off = 32; off > 0; off >>= 1) s += __shfl_down(s, off);
            if (l == 0) out[r0 + row] = s + b3[0];
        }
    }
}

extern "C" void kernel_launch(void* const* d_in, const int* in_sizes, int n_in,
                              void* d_out, int out_size, void* d_ws, size_t ws_size,
                              hipStream_t stream) {
    const float* traffic  = (const float*)d_in[0];
    const float* packets  = (const float*)d_in[1];
    const float* capacity = (const float*)d_in[2];
    const float* weight   = (const float*)d_in[3];
    const int* policy     = (const int*)d_in[4];
    const int* priority   = (const int*)d_in[5];
    const int* path_ids   = (const int*)d_in[6];
    const int* l_q_p      = (const int*)d_in[7];
    const int* l_p_s      = (const int*)d_in[8];
    const int* link_to_path    = (const int*)d_in[9];
    const int* queue_to_path   = (const int*)d_in[10];
    const int* path_to_queue   = (const int*)d_in[11];
    const int* sequence_queues = (const int*)d_in[12];
    const float* Wp  = (const float*)d_in[19];
    const float* Up  = (const float*)d_in[20];
    const float* bp  = (const float*)d_in[21];
    const float* Wl  = (const float*)d_in[22];
    const float* Ul  = (const float*)d_in[23];
    const float* bl  = (const float*)d_in[24];
    const float* Wq  = (const float*)d_in[25];
    const float* Uq  = (const float*)d_in[26];
    const float* bq  = (const float*)d_in[27];
    const float* Wr1 = (const float*)d_in[28];
    const float* br1 = (const float*)d_in[29];
    const float* Wr2 = (const float*)d_in[30];
    const float* br2 = (const float*)d_in[31];
    const float* Wr3 = (const float*)d_in[32];
    const float* br3 = (const float*)d_in[33];
    float* out = (float*)d_out;

    k_init_maps<<<(NE + 255) / 256, 256, 0, stream>>>();
    k_fill_maps<<<(NE + 255) / 256, 256, 0, stream>>>(path_ids, l_q_p, l_p_s, queue_to_path,
                                                      link_to_path, sequence_queues);
    k_scan<<<1, 1024, 0, stream>>>();
    k_fill_csr<<<(NE + 255) / 256, 256, 0, stream>>>(sequence_queues, path_to_queue);
    k_init_states<<<(NP * DD + 255) / 256, 256, 0, stream>>>(traffic, packets, capacity,
                                                             policy, weight, priority);
    k_pack<<<192, 256, 0, stream>>>(0, Up, N3);
    k_pack<<<192, 256, 0, stream>>>(1, Wp, N3);
    k_pack<<<192, 256, 0, stream>>>(2, Wp + 128 * N3, N3);
    k_pack<<<192, 256, 0, stream>>>(3, Wl, N3);
    k_pack<<<192, 256, 0, stream>>>(4, Wq, N3);
    k_pack<<<192, 256, 0, stream>>>(5, Uq, N3);
    k_pack<<<192, 256, 0, stream>>>(6, Ul, N3);
    k_pack<<<128, 256, 0, stream>>>(7, Wr1, 256);
    k_pack<<<256, 256, 0, stream>>>(8, Wr2, 256);
    k_nz<<<NQ / 4, 256, 0, stream>>>(0);
    k_nz<<<NL / 4, 256, 0, stream>>>(1);
    // initial projections (queue@Wp.q + bp0 -> qgi ; link@Wp.l -> lgi)
    k_gemm_mfma<<<NQ / 16 + NL / 16, 256, 0, stream>>>(bp);

    for (int it = 0; it < TT; ++it) {
        k_path<<<NP / 16, 512, 0, stream>>>(bp);
        k_qsum<<<NQ / 4, 256, 0, stream>>>();
        k_queue_mfma<<<NQ / 16, 256, 0, stream>>>(bq, bl, bp);  // + both queue projections
        k_link_mfma<<<NL / 16, 256, 0, stream>>>(bl);           // + link projection
    }

    k_readout_mfma<<<NP / 16, 256, 0, stream>>>(br1, br2, Wr3, br3, out);
}